// Round 7
// baseline (167.162 us; speedup 1.0000x reference)
//
#include <hip/hip_runtime.h>
#include <hip/hip_fp16.h>

// ---------------------------------------------------------------------------
// NL=16, NS=256, NE=100, B=2, P=2, T=12
// x:(2,2,12,16,256) K/Q/V:(256,256,16) Aoo:(256,256) Ann:(100,)
// Aon/Ano:(256,256,100) w:(256,)  out:(2,2,1,16)=64 fp32
// kvt[bt][X][Y] = sum_j Kh[X,j]*u[bt,j]*Qh[Y,j],  j = x*16+c  (K=4096)
// ---------------------------------------------------------------------------

using f32x4 = __attribute__((ext_vector_type(4))) float;
using half8 = __attribute__((ext_vector_type(8))) _Float16;
using half4 = __attribute__((ext_vector_type(4))) _Float16;

__device__ inline float clip1(float v) { return fminf(fmaxf(v, -1.f), 1.f); }

__device__ inline half8 mul8(uint4 a, uint4 b) {
    half8 x = __builtin_bit_cast(half8, a);
    half8 y = __builtin_bit_cast(half8, b);
    return x * y;                          // v_pk_mul_f16 x4
}

__device__ __forceinline__ void gl_lds16(const void* g, void* l) {
    __builtin_amdgcn_global_load_lds(
        (const __attribute__((address_space(1))) void*)g,
        (__attribute__((address_space(3))) void*)l, 16, 0, 0);
}

// ---------------------------------------------------------------------------
// Fused prep: [0,2048) K/Q->fp16 ; [2048,2096) u_t ; [2096,2352) W2p ;
// [2352,2608) R.  grid 2608 x 256
// ---------------------------------------------------------------------------
__global__ void prep_kernel(const float* __restrict__ K, const float* __restrict__ Q,
                            const float* __restrict__ xin,
                            const float* __restrict__ Aon, const float* __restrict__ wv,
                            const float* __restrict__ V,
                            __half* __restrict__ Kh, __half* __restrict__ Qh,
                            __half* __restrict__ u_t,
                            float* __restrict__ W2p, float* __restrict__ R)
{
    int b = blockIdx.x, t = threadIdx.x;
    if (b < 2048) {
        bool isK = (b < 1024);
        int bb = isK ? b : b - 1024;
        int i = bb * 1024 + t * 4;
        const float4 f = ((const float4*)(isK ? K : Q))[i >> 2];
        half4 v = { (_Float16)f.x, (_Float16)f.y, (_Float16)f.z, (_Float16)f.w };
        *(half4*)((isK ? Kh : Qh) + i) = v;
    } else if (b < 2096) {
        int bt = b - 2048;                    // 0..47
        const float* src = xin + (size_t)bt * 4096;
        int xx = t;                           // 0..255
        half8 lo, hi;
        #pragma unroll
        for (int c = 0; c < 8; ++c)  lo[c] = (_Float16)src[c * 256 + xx];
        #pragma unroll
        for (int c = 0; c < 8; ++c)  hi[c] = (_Float16)src[(c + 8) * 256 + xx];
        half8* dst = (half8*)(u_t + (size_t)bt * 4096 + xx * 16);
        dst[0] = lo; dst[1] = hi;
    } else if (b < 2352) {
        // W2p[g][X][n] = sum_{b in g*128..+128} w[b]*clip(Aon[X,b,n]) ; g = t>>7
        int X = b - 2096;                     // 0..255
        int g = t >> 7, n = t & 127;
        if (n < 100) {
            const float* base = Aon + (size_t)X * 25600 + (size_t)g * 12800 + n;
            float acc = 0.f;
            for (int bb = 0; bb < 128; ++bb)
                acc += wv[g * 128 + bb] * clip1(__builtin_nontemporal_load(base + (size_t)bb * 100));
            W2p[((size_t)g * 256 + X) * 100 + n] = acc;
        }
    } else {
        // R[bp][X][c] = sum_x xlast[bp][c][x] * V[X][x*16+c]
        __shared__ float vrow[4096];
        int X = b - 2352;                     // 0..255
        {
            const float4* src = (const float4*)(V + (size_t)X * 4096);
            float4* dst = (float4*)vrow;
            for (int i = t; i < 1024; i += 256) dst[i] = src[i];
        }
        __syncthreads();
        int bp = t >> 6, c = (t >> 2) & 15, g = t & 3;
        const float* xl = xin + ((size_t)(bp * 12) + 11) * 4096 + c * 256;
        float p = 0.f;
        #pragma unroll 4
        for (int x = g * 64; x < g * 64 + 64; ++x)
            p += xl[x] * vrow[x * 16 + c];
        p += __shfl_xor(p, 1);
        p += __shfl_xor(p, 2);
        if (g == 0) R[((size_t)bp * 256 + X) * 16 + c] = p;
    }
}

// ---------------------------------------------------------------------------
// GEMM: 128x128 tile, full K=4096, BK=64, double-buffered LDS staged via
// global_load_lds dwordx4 with XOR-swizzle (pre-swizzled global source).
// Counted-vmcnt 2-ahead pipeline, raw barriers (no vmcnt(0) drain in loop).
// grid 192 (= 48 bt * 4 tiles), XCD-swizzled; nontemporal epilogue stores.
// ---------------------------------------------------------------------------
__global__ __launch_bounds__(256) void gemm_kvt(
    const __half* __restrict__ Kh, const __half* __restrict__ Qh,
    const __half* __restrict__ u_t, float* __restrict__ kvt)
{
    __shared__ __half As[2][128][64];   // 32 KB
    __shared__ __half Bs[2][128][64];   // 32 KB
    __shared__ __half u_s[4096];        // 8 KB

    int bid = blockIdx.x;
    int work = (bid & 7) * 24 + (bid >> 3);    // XCD x gets contiguous tile-major works
    int tile = work / 48;
    int bt = work - tile * 48;
    int Xb = (tile >> 1) * 128, Yb = (tile & 1) * 128;

    int tid = threadIdx.x;
    {   // stage full u (4096 halves = 512 uint4)
        const uint4* src = (const uint4*)(u_t + (size_t)bt * 4096);
        uint4* dst = (uint4*)u_s;
        dst[tid] = src[tid];
        dst[tid + 256] = src[tid + 256];
    }
    __syncthreads();    // u_s visible to all waves (also drains the u global loads)

    int wave = tid >> 6, lane = tid & 63;
    int lr = lane >> 3, lk = lane & 7;
    int swz = ((lk ^ lr) << 3);                // pre-swizzled k-offset (halves)
    const __half* gA = Kh + (size_t)(Xb + wave * 32 + lr) * 4096 + swz;
    const __half* gB = Qh + (size_t)(Yb + wave * 32 + lr) * 4096 + swz;

    int wr = (wave >> 1) * 64, wc = (wave & 1) * 64;
    int lrow = lane & 15, kg = lane >> 4;

    f32x4 acc[4][4];
    f32x4 zero = {0.f, 0.f, 0.f, 0.f};
    #pragma unroll
    for (int m = 0; m < 4; ++m)
        #pragma unroll
        for (int n = 0; n < 4; ++n) acc[m][n] = zero;

    #define STAGE(s, buf)                                                      \
        do {                                                                   \
            const __half* a_ = gA + (s) * 64;                                  \
            const __half* b_ = gB + (s) * 64;                                  \
            _Pragma("unroll")                                                  \
            for (int i_ = 0; i_ < 4; ++i_) {                                   \
                gl_lds16(a_ + (size_t)(i_ * 8) * 4096, &As[buf][wave * 32 + i_ * 8][0]); \
                gl_lds16(b_ + (size_t)(i_ * 8) * 4096, &Bs[buf][wave * 32 + i_ * 8][0]); \
            }                                                                  \
        } while (0)

    STAGE(0, 0);
    STAGE(1, 1);

    for (int s = 0; s < 64; ++s) {
        // wait for this step's batch (8 oldest of our 16 outstanding), not all
        if (s < 63) asm volatile("s_waitcnt vmcnt(8)" ::: "memory");
        else        asm volatile("s_waitcnt vmcnt(0)" ::: "memory");
        __builtin_amdgcn_s_barrier();
        __builtin_amdgcn_sched_barrier(0);

        int cur = s & 1;
        #pragma unroll
        for (int kh = 0; kh < 2; ++kh) {
            uint4 uv = *(const uint4*)&u_s[s * 64 + kh * 32 + kg * 8];
            half8 af[4], bf[4];
            #pragma unroll
            for (int m = 0; m < 4; ++m) {
                int row = wr + m * 16 + lrow;
                int kbyte = (kh * 64 + kg * 16) ^ ((row & 7) << 4);
                af[m] = mul8(*(const uint4*)((const char*)&As[cur][row][0] + kbyte), uv);
            }
            #pragma unroll
            for (int n = 0; n < 4; ++n) {
                int row = wc + n * 16 + lrow;
                int kbyte = (kh * 64 + kg * 16) ^ ((row & 7) << 4);
                bf[n] = *(const half8*)((const char*)&Bs[cur][row][0] + kbyte);
            }
            #pragma unroll
            for (int m = 0; m < 4; ++m)
                #pragma unroll
                for (int n = 0; n < 4; ++n)
                    acc[m][n] = __builtin_amdgcn_mfma_f32_16x16x32_f16(af[m], bf[n], acc[m][n], 0, 0, 0);
        }

        // all our ds_reads retired; then all waves past the point -> safe to
        // overwrite buf[cur] with batch s+2
        asm volatile("s_waitcnt lgkmcnt(0)" ::: "memory");
        __builtin_amdgcn_s_barrier();
        __builtin_amdgcn_sched_barrier(0);
        if (s + 2 < 64) STAGE(s + 2, cur);
    }
    #undef STAGE

    // epilogue: D layout col = lane&15, row = (lane>>4)*4 + reg ; nt stores
    float* outp = kvt + (size_t)bt * 65536;
    int row0 = Xb + wr + kg * 4;
    int col0 = Yb + wc + lrow;
    #pragma unroll
    for (int m = 0; m < 4; ++m)
        #pragma unroll
        for (int n = 0; n < 4; ++n)
            #pragma unroll
            for (int rr = 0; rr < 4; ++rr)
                __builtin_nontemporal_store(acc[m][n][rr],
                    &outp[(size_t)(row0 + m * 16 + rr) * 256 + col0 + n * 16]);
}

// ---------------------------------------------------------------------------
// Sp[cb][bp][J][n] = sum_{k in 128-chunk cb} clip(Ano[k][n]) * kvt[bp*12+J][k]
// ---------------------------------------------------------------------------
__global__ __launch_bounds__(256) void s_partial(const float* __restrict__ Ano,
                                                 const float* __restrict__ kvt,
                                                 float* __restrict__ Sp)
{
    __shared__ float ano_f[12864];          // 128*100 + pad
    __shared__ float kvt_s[44][128];
    int cb = blockIdx.x;
    int k0 = cb * 128;
    int tid = threadIdx.x;

    {
        const f32x4* src = (const f32x4*)(Ano + (size_t)k0 * 100);
        f32x4* dst = (f32x4*)ano_f;
        for (int i = tid; i < 3200; i += 256) {
            f32x4 f = __builtin_nontemporal_load(src + i);
            f.x = clip1(f.x); f.y = clip1(f.y); f.z = clip1(f.z); f.w = clip1(f.w);
            dst[i] = f;
        }
    }
    {
        for (int idx = tid; idx < 5632; idx += 256) {
            int rI = idx >> 7, k = idx & 127;
            int bpr = rI / 11, Jr = rI - bpr * 11;
            kvt_s[rI][k] = __builtin_nontemporal_load(
                &kvt[(size_t)(bpr * 12 + Jr) * 65536 + k0 + k]);
        }
    }
    __syncthreads();

    int lane = tid & 63;
    int bp = tid >> 6;
    bool has2 = lane < 36;
    float acc0[11], acc1[11];
    #pragma unroll
    for (int J = 0; J < 11; ++J) { acc0[J] = 0.f; acc1[J] = 0.f; }

    for (int k = 0; k < 128; k += 4) {
        f32x4 kv[11];
        #pragma unroll
        for (int J = 0; J < 11; ++J)
            kv[J] = *(const f32x4*)&kvt_s[bp * 11 + J][k];
        #pragma unroll
        for (int kk = 0; kk < 4; ++kk) {
            float a0 = ano_f[(k + kk) * 100 + lane];
            float a1r = ano_f[(k + kk) * 100 + 64 + lane];
            float a1 = has2 ? a1r : 0.f;
            #pragma unroll
            for (int J = 0; J < 11; ++J) {
                acc0[J] += kv[J][kk] * a0;
                acc1[J] += kv[J][kk] * a1;
            }
        }
    }
    float* outb = Sp + ((size_t)cb * 4 + bp) * 1100;
    #pragma unroll
    for (int J = 0; J < 11; ++J) {
        outb[J * 100 + lane] = acc0[J];
        if (has2) outb[J * 100 + 64 + lane] = acc1[J];
    }
}

// Sq[qq][bp*11+J][n] = sum_{cb in quarter qq} Sp[cb][bp][J][n] ; grid 176 x 128
__global__ void reduce_s(const float* __restrict__ Sp, float* __restrict__ Sq)
{
    int bid = blockIdx.x;
    int qq = bid & 3, idx = bid >> 2;       // idx 0..43
    int bp = idx / 11, J = idx - bp * 11;
    int t = threadIdx.x;
    if (t >= 100) return;
    float acc = 0.f;
    for (int c = qq * 128; c < qq * 128 + 128; ++c)
        acc += __builtin_nontemporal_load(&Sp[((size_t)c * 4 + bp) * 1100 + J * 100 + t]);
    Sq[(size_t)(qq * 44 + idx) * 100 + t] = acc;
}

// c2[bp][n] = S[10] + sum_J A_seq[9-J]*S[J] ; also zeroes out[64] ; 1 x 512
__global__ void c2_kernel(const float* __restrict__ Sq, const float* __restrict__ Ann,
                          float* __restrict__ c2, float* __restrict__ out)
{
    int t = threadIdx.x;
    if (t < 64) out[t] = 0.f;
    int bp = t >> 7, n = t & 127;
    if (n >= 100) return;
    float S[11];
    #pragma unroll
    for (int J = 0; J < 11; ++J) {
        float s = 0.f;
        #pragma unroll
        for (int qq = 0; qq < 4; ++qq)
            s += Sq[(size_t)(qq * 44 + bp * 11 + J) * 100 + n];
        S[J] = s;
    }
    float a = Ann[n];
    float seq[10];
    float v = a;
    seq[0] = v;
    #pragma unroll
    for (int s = 1; s < 10; ++s) { v = clip1(v * a); seq[s] = v; }
    float r = S[10];
    #pragma unroll
    for (int J = 0; J < 10; ++J)
        r += seq[9 - J] * S[J];
    c2[bp * 100 + n] = r;
}

// hw[bp][X] = sum_x w[x]*Aoo[X,x]*kvt11[X,x] + sum_n c2[bp][n]*W2[X][n]
// then y partials: atomicAdd(out[bp*16+c], sum_{X in block} hw*R[bp][X][c])
// grid 256 (bp*64+Xg) x 256
__global__ __launch_bounds__(256) void hw_kernel(const float* __restrict__ Aoo,
                                                 const float* __restrict__ wv,
                                                 const float* __restrict__ kvt,
                                                 const float* __restrict__ W2p,
                                                 const float* __restrict__ c2,
                                                 const float* __restrict__ R,
                                                 float* __restrict__ out)
{
    __shared__ float yp[4][16];
    int bp = blockIdx.x >> 6, Xg = blockIdx.x & 63;
    int tid = threadIdx.x;
    int wave = tid >> 6, lane = tid & 63;
    int X = Xg * 4 + wave;
    const float* kv = kvt + (size_t)(bp * 12 + 11) * 65536 + (size_t)X * 256;
    const float* ao = Aoo + (size_t)X * 256;
    float red = 0.f;
    #pragma unroll
    for (int qq = 0; qq < 4; ++qq) {
        int xx = qq * 64 + lane;
        red += wv[xx] * ao[xx] * kv[xx];
    }
    float w2a = W2p[(size_t)X * 100 + lane] + W2p[(size_t)(256 + X) * 100 + lane];
    red += c2[bp * 100 + lane] * w2a;
    if (lane < 36) {
        float w2b = W2p[(size_t)X * 100 + 64 + lane] + W2p[(size_t)(256 + X) * 100 + 64 + lane];
        red += c2[bp * 100 + 64 + lane] * w2b;
    }
    #pragma unroll
    for (int off = 32; off; off >>= 1) red += __shfl_xor(red, off);
    // all lanes hold hw[bp][X]
    if (lane < 16) yp[wave][lane] = red * R[((size_t)bp * 256 + X) * 16 + lane];
    __syncthreads();
    if (tid < 16) {
        float s = yp[0][tid] + yp[1][tid] + yp[2][tid] + yp[3][tid];
        atomicAdd(&out[bp * 16 + tid], s);
    }
}

// ---------------------------------------------------------------------------
extern "C" void kernel_launch(void* const* d_in, const int* in_sizes, int n_in,
                              void* d_out, int out_size, void* d_ws, size_t ws_size,
                              hipStream_t stream)
{
    const float* x   = (const float*)d_in[0];
    const float* K   = (const float*)d_in[1];
    const float* Q   = (const float*)d_in[2];
    const float* V   = (const float*)d_in[3];
    const float* Aoo = (const float*)d_in[4];
    const float* Ann = (const float*)d_in[5];
    const float* Aon = (const float*)d_in[6];
    const float* Ano = (const float*)d_in[7];
    const float* wv  = (const float*)d_in[8];
    float* out = (float*)d_out;

    char* ws = (char*)d_ws;
    const size_t o_Qh   = 0;                                  // 2 MB
    const size_t o_Kh   = o_Qh + (size_t)2 * 1024 * 1024;     // 2 MB
    const size_t o_ut   = o_Kh + (size_t)2 * 1024 * 1024;     // 384 KB (pad .5 MB)
    const size_t o_kvt  = o_ut + (size_t)512 * 1024;          // 12 MB
    const size_t o_Sp   = o_kvt + (size_t)48 * 65536 * 4;     // 9 MB
    const size_t o_Sq   = o_Sp + (size_t)512 * 4400 * 4;
    const size_t o_c2   = o_Sq + (size_t)17600 * 4;
    const size_t o_W2   = o_c2 + 400 * 4 + 64;                // 2*256*100 f32
    const size_t o_R    = o_W2 + (size_t)51200 * 4;           // 4*256*16 f32

    __half* Qh  = (__half*)(ws + o_Qh);
    __half* Kh  = (__half*)(ws + o_Kh);
    __half* u_t = (__half*)(ws + o_ut);
    float* kvt  = (float*)(ws + o_kvt);
    float* Sp   = (float*)(ws + o_Sp);
    float* Sq   = (float*)(ws + o_Sq);
    float* c2   = (float*)(ws + o_c2);
    float* W2p  = (float*)(ws + o_W2);
    float* R    = (float*)(ws + o_R);

    hipLaunchKernelGGL(prep_kernel, dim3(2608), dim3(256), 0, stream,
                       K, Q, x, Aon, wv, V, Kh, Qh, u_t, W2p, R);
    hipLaunchKernelGGL(gemm_kvt,    dim3(192),  dim3(256), 0, stream, Kh, Qh, u_t, kvt);
    hipLaunchKernelGGL(s_partial,   dim3(512),  dim3(256), 0, stream, Ano, kvt, Sp);
    hipLaunchKernelGGL(reduce_s,    dim3(176),  dim3(128), 0, stream, Sp, Sq);
    hipLaunchKernelGGL(c2_kernel,   dim3(1),    dim3(512), 0, stream, Sq, Ann, c2, out);
    hipLaunchKernelGGL(hw_kernel,   dim3(256),  dim3(256), 0, stream,
                       Aoo, wv, kvt, W2p, c2, R, out);
}

// Round 8
// 123.764 us; speedup vs baseline: 1.3507x; 1.3507x over previous
//
#include <hip/hip_runtime.h>
#include <hip/hip_fp16.h>

// ---------------------------------------------------------------------------
// NL=16, NS=256, NE=100, B=2, P=2, T=12
// x:(2,2,12,16,256) K/Q/V:(256,256,16) Aoo:(256,256) Ann:(100,)
// Aon/Ano:(256,256,100) w:(256,)  out:(2,2,1,16)=64 fp32
// kvt[bt][X][Y] = sum_j Kh[X,j]*u[bt,j]*Qh[Y,j],  j = x*16+c  (K=4096)
// ---------------------------------------------------------------------------

using f32x4 = __attribute__((ext_vector_type(4))) float;
using half8 = __attribute__((ext_vector_type(8))) _Float16;
using half4 = __attribute__((ext_vector_type(4))) _Float16;

#define KVT_STRIDE 3145728ull    // 48*65536 floats per K-chunk partial
#define KS 4

__device__ inline float clip1(float v) { return fminf(fmaxf(v, -1.f), 1.f); }

__device__ inline half8 mul8(uint4 a, uint4 b) {
    half8 x = __builtin_bit_cast(half8, a);
    half8 y = __builtin_bit_cast(half8, b);
    return x * y;                          // v_pk_mul_f16 x4
}

__device__ __forceinline__ void gl_lds16(const void* g, void* l) {
    __builtin_amdgcn_global_load_lds(
        (const __attribute__((address_space(1))) void*)g,
        (__attribute__((address_space(3))) void*)l, 16, 0, 0);
}

// ---------------------------------------------------------------------------
// Fused prep: [0,2048) K/Q->fp16 ; [2048,2096) u_t ; [2096,2352) W2p ;
// [2352,2608) R.  grid 2608 x 256
// ---------------------------------------------------------------------------
__global__ void prep_kernel(const float* __restrict__ K, const float* __restrict__ Q,
                            const float* __restrict__ xin,
                            const float* __restrict__ Aon, const float* __restrict__ wv,
                            const float* __restrict__ V,
                            __half* __restrict__ Kh, __half* __restrict__ Qh,
                            __half* __restrict__ u_t,
                            float* __restrict__ W2p, float* __restrict__ R)
{
    int b = blockIdx.x, t = threadIdx.x;
    if (b < 2048) {
        bool isK = (b < 1024);
        int bb = isK ? b : b - 1024;
        int i = bb * 1024 + t * 4;
        const float4 f = ((const float4*)(isK ? K : Q))[i >> 2];
        half4 v = { (_Float16)f.x, (_Float16)f.y, (_Float16)f.z, (_Float16)f.w };
        *(half4*)((isK ? Kh : Qh) + i) = v;
    } else if (b < 2096) {
        int bt = b - 2048;                    // 0..47
        const float* src = xin + (size_t)bt * 4096;
        int xx = t;                           // 0..255
        half8 lo, hi;
        #pragma unroll
        for (int c = 0; c < 8; ++c)  lo[c] = (_Float16)src[c * 256 + xx];
        #pragma unroll
        for (int c = 0; c < 8; ++c)  hi[c] = (_Float16)src[(c + 8) * 256 + xx];
        half8* dst = (half8*)(u_t + (size_t)bt * 4096 + xx * 16);
        dst[0] = lo; dst[1] = hi;
    } else if (b < 2352) {
        // W2p[g][X][n] = sum_{b in g*128..+128} w[b]*clip(Aon[X,b,n]) ; g = t>>7
        int X = b - 2096;                     // 0..255
        int g = t >> 7, n = t & 127;
        if (n < 100) {
            const float* base = Aon + (size_t)X * 25600 + (size_t)g * 12800 + n;
            float acc = 0.f;
            for (int bb = 0; bb < 128; ++bb)
                acc += wv[g * 128 + bb] * clip1(__builtin_nontemporal_load(base + (size_t)bb * 100));
            W2p[((size_t)g * 256 + X) * 100 + n] = acc;
        }
    } else {
        // R[bp][X][c] = sum_x xlast[bp][c][x] * V[X][x*16+c]
        __shared__ float vrow[4096];
        int X = b - 2352;                     // 0..255
        {
            const float4* src = (const float4*)(V + (size_t)X * 4096);
            float4* dst = (float4*)vrow;
            for (int i = t; i < 1024; i += 256) dst[i] = src[i];
        }
        __syncthreads();
        int bp = t >> 6, c = (t >> 2) & 15, g = t & 3;
        const float* xl = xin + ((size_t)(bp * 12) + 11) * 4096 + c * 256;
        float p = 0.f;
        #pragma unroll 4
        for (int x = g * 64; x < g * 64 + 64; ++x)
            p += xl[x] * vrow[x * 16 + c];
        p += __shfl_xor(p, 1);
        p += __shfl_xor(p, 2);
        if (g == 0) R[((size_t)bp * 256 + X) * 16 + c] = p;
    }
}

// ---------------------------------------------------------------------------
// GEMM: 128x128 tile, K-chunk Kc=1024 (KS=4), BK=64, double-buffered LDS via
// global_load_lds dwordx4 with XOR-swizzle (pre-swizzled global source).
// Counted-vmcnt 2-ahead pipeline, raw barriers (no vmcnt(0) drain in loop).
// grid 768 (= 48 bt * 4 tiles * 4 kc), XCD-swizzled; 2 blocks/CU @ 66KB LDS.
// ---------------------------------------------------------------------------
__global__ __launch_bounds__(256) void gemm_kvt(
    const __half* __restrict__ Kh, const __half* __restrict__ Qh,
    const __half* __restrict__ u_t, float* __restrict__ kvtp)
{
    __shared__ __half As[2][128][64];   // 32 KB
    __shared__ __half Bs[2][128][64];   // 32 KB
    __shared__ __half u_s[1024];        // 2 KB

    int bid = blockIdx.x;
    int work = (bid & 7) * 96 + (bid >> 3);    // XCD x gets contiguous works
    int kc = work / 192;
    int rem = work - kc * 192;
    int tile = rem / 48;
    int bt = rem - tile * 48;
    int Xb = (tile >> 1) * 128, Yb = (tile & 1) * 128;
    int kbase = kc * 1024;

    int tid = threadIdx.x;
    if (tid < 128)      // stage u chunk (1024 halves = 128 uint4)
        *(uint4*)&u_s[tid * 8] = *(const uint4*)(u_t + (size_t)bt * 4096 + kbase + tid * 8);
    __syncthreads();    // u_s visible (compiler drains u load before barrier)

    int wave = tid >> 6, lane = tid & 63;
    int lr = lane >> 3, lk = lane & 7;
    int swz = ((lk ^ lr) << 3);                // pre-swizzled k-offset (halves)
    const __half* gA = Kh + (size_t)(Xb + wave * 32 + lr) * 4096 + kbase + swz;
    const __half* gB = Qh + (size_t)(Yb + wave * 32 + lr) * 4096 + kbase + swz;

    int wr = (wave >> 1) * 64, wc = (wave & 1) * 64;
    int lrow = lane & 15, kg = lane >> 4;

    f32x4 acc[4][4];
    f32x4 zero = {0.f, 0.f, 0.f, 0.f};
    #pragma unroll
    for (int m = 0; m < 4; ++m)
        #pragma unroll
        for (int n = 0; n < 4; ++n) acc[m][n] = zero;

    #define STAGE(s, buf)                                                      \
        do {                                                                   \
            const __half* a_ = gA + (s) * 64;                                  \
            const __half* b_ = gB + (s) * 64;                                  \
            _Pragma("unroll")                                                  \
            for (int i_ = 0; i_ < 4; ++i_) {                                   \
                gl_lds16(a_ + (size_t)(i_ * 8) * 4096, &As[buf][wave * 32 + i_ * 8][0]); \
                gl_lds16(b_ + (size_t)(i_ * 8) * 4096, &Bs[buf][wave * 32 + i_ * 8][0]); \
            }                                                                  \
        } while (0)

    STAGE(0, 0);
    STAGE(1, 1);

    for (int s = 0; s < 16; ++s) {
        // retire this step's batch (oldest 8 of up to 16 outstanding)
        if (s < 15) asm volatile("s_waitcnt vmcnt(8)" ::: "memory");
        else        asm volatile("s_waitcnt vmcnt(0)" ::: "memory");
        __builtin_amdgcn_s_barrier();
        __builtin_amdgcn_sched_barrier(0);

        int cur = s & 1;
        #pragma unroll
        for (int kh = 0; kh < 2; ++kh) {
            uint4 uv = *(const uint4*)&u_s[s * 64 + kh * 32 + kg * 8];
            half8 af[4], bf[4];
            #pragma unroll
            for (int m = 0; m < 4; ++m) {
                int row = wr + m * 16 + lrow;
                int kbyte = (kh * 64 + kg * 16) ^ ((row & 7) << 4);
                af[m] = mul8(*(const uint4*)((const char*)&As[cur][row][0] + kbyte), uv);
            }
            #pragma unroll
            for (int n = 0; n < 4; ++n) {
                int row = wc + n * 16 + lrow;
                int kbyte = (kh * 64 + kg * 16) ^ ((row & 7) << 4);
                bf[n] = *(const half8*)((const char*)&Bs[cur][row][0] + kbyte);
            }
            #pragma unroll
            for (int m = 0; m < 4; ++m)
                #pragma unroll
                for (int n = 0; n < 4; ++n)
                    acc[m][n] = __builtin_amdgcn_mfma_f32_16x16x32_f16(af[m], bf[n], acc[m][n], 0, 0, 0);
        }

        // our ds_reads retired, then all waves past point -> safe to restage buf
        asm volatile("s_waitcnt lgkmcnt(0)" ::: "memory");
        __builtin_amdgcn_s_barrier();
        __builtin_amdgcn_sched_barrier(0);
        if (s + 2 < 16) STAGE(s + 2, cur);
    }
    #undef STAGE

    // epilogue: D layout col = lane&15, row = (lane>>4)*4 + reg
    float* outp = kvtp + (size_t)kc * KVT_STRIDE + (size_t)bt * 65536;
    int row0 = Xb + wr + kg * 4;
    int col0 = Yb + wc + lrow;
    #pragma unroll
    for (int m = 0; m < 4; ++m)
        #pragma unroll
        for (int n = 0; n < 4; ++n)
            #pragma unroll
            for (int rr = 0; rr < 4; ++rr)
                outp[(size_t)(row0 + m * 16 + rr) * 256 + col0 + n * 16] = acc[m][n][rr];
}

// ---------------------------------------------------------------------------
// Sp[cb][bp][J][n] = sum_{k in 128-chunk cb} clip(Ano[k][n]) * kvt[bp*12+J][k]
// kvt materialized on the fly as sum of KS partials (L2/L3-resident).
// ---------------------------------------------------------------------------
__global__ __launch_bounds__(256) void s_partial(const float* __restrict__ Ano,
                                                 const float* __restrict__ kvtp,
                                                 float* __restrict__ Sp)
{
    __shared__ float ano_f[12864];          // 128*100 + pad
    __shared__ float kvt_s[44][128];
    int cb = blockIdx.x;
    int k0 = cb * 128;
    int tid = threadIdx.x;

    {
        const f32x4* src = (const f32x4*)(Ano + (size_t)k0 * 100);
        f32x4* dst = (f32x4*)ano_f;
        for (int i = tid; i < 3200; i += 256) {
            f32x4 f = __builtin_nontemporal_load(src + i);
            f.x = clip1(f.x); f.y = clip1(f.y); f.z = clip1(f.z); f.w = clip1(f.w);
            dst[i] = f;
        }
    }
    {
        for (int idx = tid; idx < 5632; idx += 256) {
            int rI = idx >> 7, k = idx & 127;
            int bpr = rI / 11, Jr = rI - bpr * 11;
            size_t off = (size_t)(bpr * 12 + Jr) * 65536 + k0 + k;
            float v = 0.f;
            #pragma unroll
            for (int c = 0; c < KS; ++c) v += kvtp[(size_t)c * KVT_STRIDE + off];
            kvt_s[rI][k] = v;
        }
    }
    __syncthreads();

    int lane = tid & 63;
    int bp = tid >> 6;
    bool has2 = lane < 36;
    float acc0[11], acc1[11];
    #pragma unroll
    for (int J = 0; J < 11; ++J) { acc0[J] = 0.f; acc1[J] = 0.f; }

    for (int k = 0; k < 128; k += 4) {
        f32x4 kv[11];
        #pragma unroll
        for (int J = 0; J < 11; ++J)
            kv[J] = *(const f32x4*)&kvt_s[bp * 11 + J][k];
        #pragma unroll
        for (int kk = 0; kk < 4; ++kk) {
            float a0 = ano_f[(k + kk) * 100 + lane];
            float a1r = ano_f[(k + kk) * 100 + 64 + lane];
            float a1 = has2 ? a1r : 0.f;
            #pragma unroll
            for (int J = 0; J < 11; ++J) {
                acc0[J] += kv[J][kk] * a0;
                acc1[J] += kv[J][kk] * a1;
            }
        }
    }
    float* outb = Sp + ((size_t)cb * 4 + bp) * 1100;
    #pragma unroll
    for (int J = 0; J < 11; ++J) {
        outb[J * 100 + lane] = acc0[J];
        if (has2) outb[J * 100 + 64 + lane] = acc1[J];
    }
}

// Sq[qq][bp*11+J][n] = sum_{cb in quarter qq} Sp[cb][bp][J][n] ; grid 176 x 128
__global__ void reduce_s(const float* __restrict__ Sp, float* __restrict__ Sq)
{
    int bid = blockIdx.x;
    int qq = bid & 3, idx = bid >> 2;       // idx 0..43
    int bp = idx / 11, J = idx - bp * 11;
    int t = threadIdx.x;
    if (t >= 100) return;
    float acc = 0.f;
    for (int c = qq * 128; c < qq * 128 + 128; ++c)
        acc += Sp[((size_t)c * 4 + bp) * 1100 + J * 100 + t];
    Sq[(size_t)(qq * 44 + idx) * 100 + t] = acc;
}

// c2[bp][n] = S[10] + sum_J A_seq[9-J]*S[J] ; also zeroes out[64] ; 1 x 512
__global__ void c2_kernel(const float* __restrict__ Sq, const float* __restrict__ Ann,
                          float* __restrict__ c2, float* __restrict__ out)
{
    int t = threadIdx.x;
    if (t < 64) out[t] = 0.f;
    int bp = t >> 7, n = t & 127;
    if (n >= 100) return;
    float S[11];
    #pragma unroll
    for (int J = 0; J < 11; ++J) {
        float s = 0.f;
        #pragma unroll
        for (int qq = 0; qq < 4; ++qq)
            s += Sq[(size_t)(qq * 44 + bp * 11 + J) * 100 + n];
        S[J] = s;
    }
    float a = Ann[n];
    float seq[10];
    float v = a;
    seq[0] = v;
    #pragma unroll
    for (int s = 1; s < 10; ++s) { v = clip1(v * a); seq[s] = v; }
    float r = S[10];
    #pragma unroll
    for (int J = 0; J < 10; ++J)
        r += seq[9 - J] * S[J];
    c2[bp * 100 + n] = r;
}

// hw[bp][X] = sum_x w[x]*Aoo[X,x]*kvt11[X,x] + sum_n c2[bp][n]*W2[X][n]
// then y partials: atomicAdd(out[bp*16+c], sum_{X in block} hw*R[bp][X][c])
// grid 256 (bp*64+Xg) x 256
__global__ __launch_bounds__(256) void hw_kernel(const float* __restrict__ Aoo,
                                                 const float* __restrict__ wv,
                                                 const float* __restrict__ kvtp,
                                                 const float* __restrict__ W2p,
                                                 const float* __restrict__ c2,
                                                 const float* __restrict__ R,
                                                 float* __restrict__ out)
{
    __shared__ float yp[4][16];
    int bp = blockIdx.x >> 6, Xg = blockIdx.x & 63;
    int tid = threadIdx.x;
    int wave = tid >> 6, lane = tid & 63;
    int X = Xg * 4 + wave;
    size_t base = (size_t)(bp * 12 + 11) * 65536 + (size_t)X * 256;
    const float* ao = Aoo + (size_t)X * 256;
    float red = 0.f;
    #pragma unroll
    for (int qq = 0; qq < 4; ++qq) {
        int xx = qq * 64 + lane;
        float kvv = 0.f;
        #pragma unroll
        for (int c = 0; c < KS; ++c) kvv += kvtp[(size_t)c * KVT_STRIDE + base + xx];
        red += wv[xx] * ao[xx] * kvv;
    }
    float w2a = W2p[(size_t)X * 100 + lane] + W2p[(size_t)(256 + X) * 100 + lane];
    red += c2[bp * 100 + lane] * w2a;
    if (lane < 36) {
        float w2b = W2p[(size_t)X * 100 + 64 + lane] + W2p[(size_t)(256 + X) * 100 + 64 + lane];
        red += c2[bp * 100 + 64 + lane] * w2b;
    }
    #pragma unroll
    for (int off = 32; off; off >>= 1) red += __shfl_xor(red, off);
    // all lanes hold hw[bp][X]
    if (lane < 16) yp[wave][lane] = red * R[((size_t)bp * 256 + X) * 16 + lane];
    __syncthreads();
    if (tid < 16) {
        float s = yp[0][tid] + yp[1][tid] + yp[2][tid] + yp[3][tid];
        atomicAdd(&out[bp * 16 + tid], s);
    }
}

// ---------------------------------------------------------------------------
extern "C" void kernel_launch(void* const* d_in, const int* in_sizes, int n_in,
                              void* d_out, int out_size, void* d_ws, size_t ws_size,
                              hipStream_t stream)
{
    const float* x   = (const float*)d_in[0];
    const float* K   = (const float*)d_in[1];
    const float* Q   = (const float*)d_in[2];
    const float* V   = (const float*)d_in[3];
    const float* Aoo = (const float*)d_in[4];
    const float* Ann = (const float*)d_in[5];
    const float* Aon = (const float*)d_in[6];
    const float* Ano = (const float*)d_in[7];
    const float* wv  = (const float*)d_in[8];
    float* out = (float*)d_out;

    char* ws = (char*)d_ws;
    const size_t o_Qh   = 0;                                  // 2 MB
    const size_t o_Kh   = o_Qh + (size_t)2 * 1024 * 1024;     // 2 MB
    const size_t o_ut   = o_Kh + (size_t)2 * 1024 * 1024;     // 384 KB (pad .5 MB)
    const size_t o_kvtp = o_ut + (size_t)512 * 1024;          // KS*12 MB
    const size_t o_Sp   = o_kvtp + (size_t)KS * KVT_STRIDE * 4;
    const size_t o_Sq   = o_Sp + (size_t)512 * 4400 * 4;
    const size_t o_c2   = o_Sq + (size_t)17600 * 4;
    const size_t o_W2   = o_c2 + 400 * 4 + 64;                // 2*256*100 f32
    const size_t o_R    = o_W2 + (size_t)51200 * 4;           // 4*256*16 f32

    __half* Qh  = (__half*)(ws + o_Qh);
    __half* Kh  = (__half*)(ws + o_Kh);
    __half* u_t = (__half*)(ws + o_ut);
    float* kvtp = (float*)(ws + o_kvtp);
    float* Sp   = (float*)(ws + o_Sp);
    float* Sq   = (float*)(ws + o_Sq);
    float* c2   = (float*)(ws + o_c2);
    float* W2p  = (float*)(ws + o_W2);
    float* R    = (float*)(ws + o_R);

    hipLaunchKernelGGL(prep_kernel, dim3(2608), dim3(256), 0, stream,
                       K, Q, x, Aon, wv, V, Kh, Qh, u_t, W2p, R);
    hipLaunchKernelGGL(gemm_kvt,    dim3(768),  dim3(256), 0, stream, Kh, Qh, u_t, kvtp);
    hipLaunchKernelGGL(s_partial,   dim3(512),  dim3(256), 0, stream, Ano, kvtp, Sp);
    hipLaunchKernelGGL(reduce_s,    dim3(176),  dim3(128), 0, stream, Sp, Sq);
    hipLaunchKernelGGL(c2_kernel,   dim3(1),    dim3(512), 0, stream, Sq, Ann, c2, out);
    hipLaunchKernelGGL(hw_kernel,   dim3(256),  dim3(256), 0, stream,
                       Aoo, wv, kvtp, W2p, c2, R, out);
}

// Round 9
// 108.962 us; speedup vs baseline: 1.5341x; 1.1358x over previous
//
#include <hip/hip_runtime.h>
#include <hip/hip_fp16.h>

// ---------------------------------------------------------------------------
// NL=16, NS=256, NE=100, B=2, P=2, T=12
// x:(2,2,12,16,256) K/Q/V:(256,256,16) Aoo:(256,256) Ann:(100,)
// Aon/Ano:(256,256,100) w:(256,)  out:(2,2,1,16)=64 fp32
// kvt[bt][X][Y] = sum_j Kh[X,j]*u[bt,j]*Qh[Y,j],  j = x*16+c  (K=4096)
// ---------------------------------------------------------------------------

using f32x4 = __attribute__((ext_vector_type(4))) float;
using half8 = __attribute__((ext_vector_type(8))) _Float16;
using half4 = __attribute__((ext_vector_type(4))) _Float16;

#define KVT_STRIDE 3145728ull    // 48*65536 floats per K-chunk partial
#define KS 4

__device__ inline float clip1(float v) { return fminf(fmaxf(v, -1.f), 1.f); }

__device__ inline half8 mul8(uint4 a, uint4 b) {
    half8 x = __builtin_bit_cast(half8, a);
    half8 y = __builtin_bit_cast(half8, b);
    return x * y;                          // v_pk_mul_f16 x4
}

__device__ __forceinline__ void gl_lds16(const void* g, void* l) {
    __builtin_amdgcn_global_load_lds(
        (const __attribute__((address_space(1))) void*)g,
        (__attribute__((address_space(3))) void*)l, 16, 0, 0);
}

// ---------------------------------------------------------------------------
// Fused prep: [0,2048) K/Q->fp16 ; [2048,2096) u_t ; [2096,2608) W2p (4 grp);
// [2608,2864) R.  grid 2864 x 256
// ---------------------------------------------------------------------------
__global__ void prep_kernel(const float* __restrict__ K, const float* __restrict__ Q,
                            const float* __restrict__ xin,
                            const float* __restrict__ Aon, const float* __restrict__ wv,
                            const float* __restrict__ V,
                            __half* __restrict__ Kh, __half* __restrict__ Qh,
                            __half* __restrict__ u_t,
                            float* __restrict__ W2p, float* __restrict__ R)
{
    int b = blockIdx.x, t = threadIdx.x;
    if (b < 2048) {
        bool isK = (b < 1024);
        int bb = isK ? b : b - 1024;
        int i = bb * 1024 + t * 4;
        const float4 f = ((const float4*)(isK ? K : Q))[i >> 2];
        half4 v = { (_Float16)f.x, (_Float16)f.y, (_Float16)f.z, (_Float16)f.w };
        *(half4*)((isK ? Kh : Qh) + i) = v;
    } else if (b < 2096) {
        int bt = b - 2048;                    // 0..47
        const float* src = xin + (size_t)bt * 4096;
        int xx = t;                           // 0..255
        half8 lo, hi;
        #pragma unroll
        for (int c = 0; c < 8; ++c)  lo[c] = (_Float16)src[c * 256 + xx];
        #pragma unroll
        for (int c = 0; c < 8; ++c)  hi[c] = (_Float16)src[(c + 8) * 256 + xx];
        half8* dst = (half8*)(u_t + (size_t)bt * 4096 + xx * 16);
        dst[0] = lo; dst[1] = hi;
    } else if (b < 2608) {
        // W2p[g][X][n] = sum_{b in g*64..+64} w[b]*clip(Aon[X,b,n])
        int idx = b - 2096;                   // 0..511
        int X = idx >> 1, h = idx & 1;
        int g = h * 2 + (t >> 7), n = t & 127;
        if (n < 100) {
            const float* base = Aon + (size_t)X * 25600 + (size_t)g * 6400 + n;
            float acc = 0.f;
            for (int bb = 0; bb < 64; ++bb)
                acc += wv[g * 64 + bb] * clip1(__builtin_nontemporal_load(base + (size_t)bb * 100));
            W2p[((size_t)g * 256 + X) * 100 + n] = acc;
        }
    } else {
        // R[bp][X][c] = sum_x xlast[bp][c][x] * V[X][x*16+c]
        __shared__ float vrow[4096];
        int X = b - 2608;                     // 0..255
        {
            const float4* src = (const float4*)(V + (size_t)X * 4096);
            float4* dst = (float4*)vrow;
            for (int i = t; i < 1024; i += 256) dst[i] = src[i];
        }
        __syncthreads();
        int bp = t >> 6, c = (t >> 2) & 15, g = t & 3;
        const float* xl = xin + ((size_t)(bp * 12) + 11) * 4096 + c * 256;
        float p = 0.f;
        #pragma unroll 4
        for (int x = g * 64; x < g * 64 + 64; ++x)
            p += xl[x] * vrow[x * 16 + c];
        p += __shfl_xor(p, 1);
        p += __shfl_xor(p, 2);
        if (g == 0) R[((size_t)bp * 256 + X) * 16 + c] = p;
    }
}

// ---------------------------------------------------------------------------
// GEMM: 128x128 tile, K-chunk Kc=1024 (KS=4), BK=32, double-buffered LDS via
// global_load_lds dwordx4, 4-slot XOR swizzle (pre-swizzled global source).
// Counted-vmcnt 2-ahead; LDS 34 KB -> 4 blocks/CU capacity, all 768 resident.
// ---------------------------------------------------------------------------
__global__ __launch_bounds__(256, 4) void gemm_kvt(
    const __half* __restrict__ Kh, const __half* __restrict__ Qh,
    const __half* __restrict__ u_t, float* __restrict__ kvtp)
{
    __shared__ __half As[2][128][32];   // 8 KB per buf
    __shared__ __half Bs[2][128][32];
    __shared__ __half u_s[1024];        // 2 KB

    int bid = blockIdx.x;
    int work = (bid & 7) * 96 + (bid >> 3);    // XCD x gets contiguous works
    int kc = work / 192;
    int rem = work - kc * 192;
    int tile = rem / 48;
    int bt = rem - tile * 48;
    int Xb = (tile >> 1) * 128, Yb = (tile & 1) * 128;
    int kbase = kc * 1024;

    int tid = threadIdx.x;
    if (tid < 128)      // stage u chunk (1024 halves = 128 uint4)
        *(uint4*)&u_s[tid * 8] = *(const uint4*)(u_t + (size_t)bt * 4096 + kbase + tid * 8);
    __syncthreads();    // drains u load; issued BEFORE main prefetch

    int wave = tid >> 6, lane = tid & 63;
    // staging: lane covers row (i*64 + wave*16 + (lane>>2)), swizzled k-slot
    int srow = lane >> 2;                               // 0..15
    int sk = ((lane & 3) ^ (srow & 3)) * 8;             // swizzled k-off (halves)
    const __half* gA = Kh + (size_t)(Xb + wave * 16 + srow) * 4096 + kbase + sk;
    const __half* gB = Qh + (size_t)(Yb + wave * 16 + srow) * 4096 + kbase + sk;

    int wr = (wave >> 1) * 64, wc = (wave & 1) * 64;
    int lrow = lane & 15, kg = lane >> 4;
    int fb = (kg * 16) ^ ((lrow & 3) << 4);             // frag read byte in row

    f32x4 acc[4][4];
    f32x4 zero = {0.f, 0.f, 0.f, 0.f};
    #pragma unroll
    for (int m = 0; m < 4; ++m)
        #pragma unroll
        for (int n = 0; n < 4; ++n) acc[m][n] = zero;

    // 4 gl_lds per wave per stage (A i=0,1 ; B i=0,1)
    #define STAGE(s, buf)                                                      \
        do {                                                                   \
            _Pragma("unroll")                                                  \
            for (int i_ = 0; i_ < 2; ++i_) {                                   \
                gl_lds16(gA + (size_t)(i_ * 64) * 4096 + (s) * 32,             \
                         &As[buf][i_ * 64 + wave * 16][0]);                    \
                gl_lds16(gB + (size_t)(i_ * 64) * 4096 + (s) * 32,             \
                         &Bs[buf][i_ * 64 + wave * 16][0]);                    \
            }                                                                  \
        } while (0)

    STAGE(0, 0);
    STAGE(1, 1);

    for (int s = 0; s < 32; ++s) {
        // retire this step's 4 loads (oldest of 8 outstanding)
        if (s < 31) asm volatile("s_waitcnt vmcnt(4)" ::: "memory");
        else        asm volatile("s_waitcnt vmcnt(0)" ::: "memory");
        __builtin_amdgcn_s_barrier();
        __builtin_amdgcn_sched_barrier(0);

        int cur = s & 1;
        uint4 uv = *(const uint4*)&u_s[s * 32 + kg * 8];
        half8 af[4], bf[4];
        #pragma unroll
        for (int m = 0; m < 4; ++m)
            af[m] = mul8(*(const uint4*)((const char*)&As[cur][wr + m * 16 + lrow][0] + fb), uv);
        #pragma unroll
        for (int n = 0; n < 4; ++n)
            bf[n] = *(const half8*)((const char*)&Bs[cur][wc + n * 16 + lrow][0] + fb);
        #pragma unroll
        for (int m = 0; m < 4; ++m)
            #pragma unroll
            for (int n = 0; n < 4; ++n)
                acc[m][n] = __builtin_amdgcn_mfma_f32_16x16x32_f16(af[m], bf[n], acc[m][n], 0, 0, 0);

        // my ds_reads retired + all waves past -> safe to restage buf cur
        asm volatile("s_waitcnt lgkmcnt(0)" ::: "memory");
        __builtin_amdgcn_s_barrier();
        __builtin_amdgcn_sched_barrier(0);
        if (s + 2 < 32) STAGE(s + 2, cur);
    }
    #undef STAGE

    // epilogue: D layout col = lane&15, row = (lane>>4)*4 + reg
    float* outp = kvtp + (size_t)kc * KVT_STRIDE + (size_t)bt * 65536;
    int row0 = Xb + wr + kg * 4;
    int col0 = Yb + wc + lrow;
    #pragma unroll
    for (int m = 0; m < 4; ++m)
        #pragma unroll
        for (int n = 0; n < 4; ++n)
            #pragma unroll
            for (int rr = 0; rr < 4; ++rr)
                outp[(size_t)(row0 + m * 16 + rr) * 256 + col0 + n * 16] = acc[m][n][rr];
}

// ---------------------------------------------------------------------------
// Sp[cb][bp][J][n] = sum_{k in 128-chunk cb} clip(Ano[k][n]) * kvt[bp*12+J][k]
// kvt materialized on the fly as sum of KS partials (L2/L3-resident).
// ---------------------------------------------------------------------------
__global__ __launch_bounds__(256) void s_partial(const float* __restrict__ Ano,
                                                 const float* __restrict__ kvtp,
                                                 float* __restrict__ Sp)
{
    __shared__ float ano_f[12864];          // 128*100 + pad
    __shared__ float kvt_s[44][128];
    int cb = blockIdx.x;
    int k0 = cb * 128;
    int tid = threadIdx.x;

    {
        const f32x4* src = (const f32x4*)(Ano + (size_t)k0 * 100);
        f32x4* dst = (f32x4*)ano_f;
        for (int i = tid; i < 3200; i += 256) {
            f32x4 f = __builtin_nontemporal_load(src + i);
            f.x = clip1(f.x); f.y = clip1(f.y); f.z = clip1(f.z); f.w = clip1(f.w);
            dst[i] = f;
        }
    }
    {
        for (int idx = tid; idx < 5632; idx += 256) {
            int rI = idx >> 7, k = idx & 127;
            int bpr = rI / 11, Jr = rI - bpr * 11;
            size_t off = (size_t)(bpr * 12 + Jr) * 65536 + k0 + k;
            float v = 0.f;
            #pragma unroll
            for (int c = 0; c < KS; ++c) v += kvtp[(size_t)c * KVT_STRIDE + off];
            kvt_s[rI][k] = v;
        }
    }
    __syncthreads();

    int lane = tid & 63;
    int bp = tid >> 6;
    bool has2 = lane < 36;
    float acc0[11], acc1[11];
    #pragma unroll
    for (int J = 0; J < 11; ++J) { acc0[J] = 0.f; acc1[J] = 0.f; }

    for (int k = 0; k < 128; k += 4) {
        f32x4 kv[11];
        #pragma unroll
        for (int J = 0; J < 11; ++J)
            kv[J] = *(const f32x4*)&kvt_s[bp * 11 + J][k];
        #pragma unroll
        for (int kk = 0; kk < 4; ++kk) {
            float a0 = ano_f[(k + kk) * 100 + lane];
            float a1r = ano_f[(k + kk) * 100 + 64 + lane];
            float a1 = has2 ? a1r : 0.f;
            #pragma unroll
            for (int J = 0; J < 11; ++J) {
                acc0[J] += kv[J][kk] * a0;
                acc1[J] += kv[J][kk] * a1;
            }
        }
    }
    float* outb = Sp + ((size_t)cb * 4 + bp) * 1100;
    #pragma unroll
    for (int J = 0; J < 11; ++J) {
        outb[J * 100 + lane] = acc0[J];
        if (has2) outb[J * 100 + 64 + lane] = acc1[J];
    }
}

// Sq[qq][bp*11+J][n] = sum_{cb in quarter qq} Sp[cb][bp][J][n] ; grid 176 x 128
__global__ void reduce_s(const float* __restrict__ Sp, float* __restrict__ Sq)
{
    int bid = blockIdx.x;
    int qq = bid & 3, idx = bid >> 2;       // idx 0..43
    int bp = idx / 11, J = idx - bp * 11;
    int t = threadIdx.x;
    if (t >= 100) return;
    float acc = 0.f;
    for (int c = qq * 128; c < qq * 128 + 128; ++c)
        acc += Sp[((size_t)c * 4 + bp) * 1100 + J * 100 + t];
    Sq[(size_t)(qq * 44 + idx) * 100 + t] = acc;
}

// c2[bp][n] = S[10] + sum_J A_seq[9-J]*S[J] ; also zeroes out[64] ; 1 x 512
__global__ void c2_kernel(const float* __restrict__ Sq, const float* __restrict__ Ann,
                          float* __restrict__ c2, float* __restrict__ out)
{
    int t = threadIdx.x;
    if (t < 64) out[t] = 0.f;
    int bp = t >> 7, n = t & 127;
    if (n >= 100) return;
    float S[11];
    #pragma unroll
    for (int J = 0; J < 11; ++J) {
        float s = 0.f;
        #pragma unroll
        for (int qq = 0; qq < 4; ++qq)
            s += Sq[(size_t)(qq * 44 + bp * 11 + J) * 100 + n];
        S[J] = s;
    }
    float a = Ann[n];
    float seq[10];
    float v = a;
    seq[0] = v;
    #pragma unroll
    for (int s = 1; s < 10; ++s) { v = clip1(v * a); seq[s] = v; }
    float r = S[10];
    #pragma unroll
    for (int J = 0; J < 10; ++J)
        r += seq[9 - J] * S[J];
    c2[bp * 100 + n] = r;
}

// hw[bp][X] = sum_x w[x]*Aoo[X,x]*kvt11[X,x] + sum_n c2[bp][n]*W2[X][n]
// then y partials: atomicAdd(out[bp*16+c], sum_{X in block} hw*R[bp][X][c])
// grid 256 (bp*64+Xg) x 256
__global__ __launch_bounds__(256) void hw_kernel(const float* __restrict__ Aoo,
                                                 const float* __restrict__ wv,
                                                 const float* __restrict__ kvtp,
                                                 const float* __restrict__ W2p,
                                                 const float* __restrict__ c2,
                                                 const float* __restrict__ R,
                                                 float* __restrict__ out)
{
    __shared__ float yp[4][16];
    int bp = blockIdx.x >> 6, Xg = blockIdx.x & 63;
    int tid = threadIdx.x;
    int wave = tid >> 6, lane = tid & 63;
    int X = Xg * 4 + wave;
    size_t base = (size_t)(bp * 12 + 11) * 65536 + (size_t)X * 256;
    const float* ao = Aoo + (size_t)X * 256;
    float red = 0.f;
    #pragma unroll
    for (int qq = 0; qq < 4; ++qq) {
        int xx = qq * 64 + lane;
        float kvv = 0.f;
        #pragma unroll
        for (int c = 0; c < KS; ++c) kvv += kvtp[(size_t)c * KVT_STRIDE + base + xx];
        red += wv[xx] * ao[xx] * kvv;
    }
    float w2a = 0.f, w2b = 0.f;
    #pragma unroll
    for (int g = 0; g < 4; ++g) {
        w2a += W2p[((size_t)g * 256 + X) * 100 + lane];
        if (lane < 36) w2b += W2p[((size_t)g * 256 + X) * 100 + 64 + lane];
    }
    red += c2[bp * 100 + lane] * w2a;
    if (lane < 36)
        red += c2[bp * 100 + 64 + lane] * w2b;
    #pragma unroll
    for (int off = 32; off; off >>= 1) red += __shfl_xor(red, off);
    // all lanes hold hw[bp][X]
    if (lane < 16) yp[wave][lane] = red * R[((size_t)bp * 256 + X) * 16 + lane];
    __syncthreads();
    if (tid < 16) {
        float s = yp[0][tid] + yp[1][tid] + yp[2][tid] + yp[3][tid];
        atomicAdd(&out[bp * 16 + tid], s);
    }
}

// ---------------------------------------------------------------------------
extern "C" void kernel_launch(void* const* d_in, const int* in_sizes, int n_in,
                              void* d_out, int out_size, void* d_ws, size_t ws_size,
                              hipStream_t stream)
{
    const float* x   = (const float*)d_in[0];
    const float* K   = (const float*)d_in[1];
    const float* Q   = (const float*)d_in[2];
    const float* V   = (const float*)d_in[3];
    const float* Aoo = (const float*)d_in[4];
    const float* Ann = (const float*)d_in[5];
    const float* Aon = (const float*)d_in[6];
    const float* Ano = (const float*)d_in[7];
    const float* wv  = (const float*)d_in[8];
    float* out = (float*)d_out;

    char* ws = (char*)d_ws;
    const size_t o_Qh   = 0;                                  // 2 MB
    const size_t o_Kh   = o_Qh + (size_t)2 * 1024 * 1024;     // 2 MB
    const size_t o_ut   = o_Kh + (size_t)2 * 1024 * 1024;     // 384 KB (pad .5 MB)
    const size_t o_kvtp = o_ut + (size_t)512 * 1024;          // KS*12 MB
    const size_t o_Sp   = o_kvtp + (size_t)KS * KVT_STRIDE * 4;
    const size_t o_Sq   = o_Sp + (size_t)512 * 4400 * 4;
    const size_t o_c2   = o_Sq + (size_t)17600 * 4;
    const size_t o_W2   = o_c2 + 400 * 4 + 64;                // 4*256*100 f32
    const size_t o_R    = o_W2 + (size_t)102400 * 4;          // 4*256*16 f32

    __half* Qh  = (__half*)(ws + o_Qh);
    __half* Kh  = (__half*)(ws + o_Kh);
    __half* u_t = (__half*)(ws + o_ut);
    float* kvtp = (float*)(ws + o_kvtp);
    float* Sp   = (float*)(ws + o_Sp);
    float* Sq   = (float*)(ws + o_Sq);
    float* c2   = (float*)(ws + o_c2);
    float* W2p  = (float*)(ws + o_W2);
    float* R    = (float*)(ws + o_R);

    hipLaunchKernelGGL(prep_kernel, dim3(2864), dim3(256), 0, stream,
                       K, Q, x, Aon, wv, V, Kh, Qh, u_t, W2p, R);
    hipLaunchKernelGGL(gemm_kvt,    dim3(768),  dim3(256), 0, stream, Kh, Qh, u_t, kvtp);
    hipLaunchKernelGGL(s_partial,   dim3(512),  dim3(256), 0, stream, Ano, kvtp, Sp);
    hipLaunchKernelGGL(reduce_s,    dim3(176),  dim3(128), 0, stream, Sp, Sq);
    hipLaunchKernelGGL(c2_kernel,   dim3(1),    dim3(512), 0, stream, Sq, Ann, c2, out);
    hipLaunchKernelGGL(hw_kernel,   dim3(256),  dim3(256), 0, stream,
                       Aoo, wv, kvtp, W2p, c2, R, out);
}

// Round 10
// 105.150 us; speedup vs baseline: 1.5897x; 1.0363x over previous
//
#include <hip/hip_runtime.h>
#include <hip/hip_fp16.h>

// ---------------------------------------------------------------------------
// NL=16, NS=256, NE=100, B=2, P=2, T=12
// x:(2,2,12,16,256) K/Q/V:(256,256,16) Aoo:(256,256) Ann:(100,)
// Aon/Ano:(256,256,100) w:(256,)  out:(2,2,1,16)=64 fp32
// kvt[bt][X][Y] = sum_j Kh[X,j]*u[bt,j]*Qh[Y,j],  j = x*16+c  (K=4096)
// ---------------------------------------------------------------------------

using f32x4 = __attribute__((ext_vector_type(4))) float;
using half8 = __attribute__((ext_vector_type(8))) _Float16;
using half4 = __attribute__((ext_vector_type(4))) _Float16;

#define KVT_STRIDE 3145728ull    // 48*65536 halves per K-chunk partial
#define KS 4

__device__ inline float clip1(float v) { return fminf(fmaxf(v, -1.f), 1.f); }

__device__ inline half8 mul8(uint4 a, uint4 b) {
    half8 x = __builtin_bit_cast(half8, a);
    half8 y = __builtin_bit_cast(half8, b);
    return x * y;                          // v_pk_mul_f16 x4
}

__device__ __forceinline__ void gl_lds16(const void* g, void* l) {
    __builtin_amdgcn_global_load_lds(
        (const __attribute__((address_space(1))) void*)g,
        (__attribute__((address_space(3))) void*)l, 16, 0, 0);
}

// ---------------------------------------------------------------------------
// Fused prep: [0,2048) K/Q->fp16 ; [2048,2096) u_t ; [2096,2608) W2p (4 grp);
// [2608,2864) R.  grid 2864 x 256
// ---------------------------------------------------------------------------
__global__ void prep_kernel(const float* __restrict__ K, const float* __restrict__ Q,
                            const float* __restrict__ xin,
                            const float* __restrict__ Aon, const float* __restrict__ wv,
                            const float* __restrict__ V,
                            __half* __restrict__ Kh, __half* __restrict__ Qh,
                            __half* __restrict__ u_t,
                            float* __restrict__ W2p, float* __restrict__ R)
{
    int b = blockIdx.x, t = threadIdx.x;
    if (b < 2048) {
        bool isK = (b < 1024);
        int bb = isK ? b : b - 1024;
        int i = bb * 1024 + t * 4;
        const float4 f = ((const float4*)(isK ? K : Q))[i >> 2];
        half4 v = { (_Float16)f.x, (_Float16)f.y, (_Float16)f.z, (_Float16)f.w };
        *(half4*)((isK ? Kh : Qh) + i) = v;
    } else if (b < 2096) {
        int bt = b - 2048;                    // 0..47
        const float* src = xin + (size_t)bt * 4096;
        int xx = t;                           // 0..255
        half8 lo, hi;
        #pragma unroll
        for (int c = 0; c < 8; ++c)  lo[c] = (_Float16)src[c * 256 + xx];
        #pragma unroll
        for (int c = 0; c < 8; ++c)  hi[c] = (_Float16)src[(c + 8) * 256 + xx];
        half8* dst = (half8*)(u_t + (size_t)bt * 4096 + xx * 16);
        dst[0] = lo; dst[1] = hi;
    } else if (b < 2608) {
        // W2p[g][X][n] = sum_{b in g*64..+64} w[b]*clip(Aon[X,b,n])
        int idx = b - 2096;                   // 0..511
        int X = idx >> 1, h = idx & 1;
        int g = h * 2 + (t >> 7), n = t & 127;
        if (n < 100) {
            const float* base = Aon + (size_t)X * 25600 + (size_t)g * 6400 + n;
            float acc = 0.f;
            for (int bb = 0; bb < 64; ++bb)
                acc += wv[g * 64 + bb] * clip1(__builtin_nontemporal_load(base + (size_t)bb * 100));
            W2p[((size_t)g * 256 + X) * 100 + n] = acc;
        }
    } else {
        // R[bp][X][c] = sum_x xlast[bp][c][x] * V[X][x*16+c]
        __shared__ float vrow[4096];
        int X = b - 2608;                     // 0..255
        {
            const float4* src = (const float4*)(V + (size_t)X * 4096);
            float4* dst = (float4*)vrow;
            for (int i = t; i < 1024; i += 256) dst[i] = src[i];
        }
        __syncthreads();
        int bp = t >> 6, c = (t >> 2) & 15, g = t & 3;
        const float* xl = xin + ((size_t)(bp * 12) + 11) * 4096 + c * 256;
        float p = 0.f;
        #pragma unroll 4
        for (int x = g * 64; x < g * 64 + 64; ++x)
            p += xl[x] * vrow[x * 16 + c];
        p += __shfl_xor(p, 1);
        p += __shfl_xor(p, 2);
        if (g == 0) R[((size_t)bp * 256 + X) * 16 + c] = p;
    }
}

// ---------------------------------------------------------------------------
// GEMM: 128x128 tile, K-chunk Kc=1024 (KS=4), BK=32, double-buffered LDS via
// global_load_lds dwordx4, 8-group XOR swizzle (kslot ^ (row>>1)&3, via
// pre-swizzled global source). Counted-vmcnt 2-ahead; LDS 34 KB -> 4 blk/CU.
// fp16 partial output.
// ---------------------------------------------------------------------------
__global__ __launch_bounds__(256, 4) void gemm_kvt(
    const __half* __restrict__ Kh, const __half* __restrict__ Qh,
    const __half* __restrict__ u_t, __half* __restrict__ kvtp)
{
    __shared__ __half As[2][128][32];   // 8 KB per buf
    __shared__ __half Bs[2][128][32];
    __shared__ __half u_s[1024];        // 2 KB

    int bid = blockIdx.x;
    int work = (bid & 7) * 96 + (bid >> 3);    // XCD x gets contiguous works
    int kc = work / 192;
    int rem = work - kc * 192;
    int tile = rem / 48;
    int bt = rem - tile * 48;
    int Xb = (tile >> 1) * 128, Yb = (tile & 1) * 128;
    int kbase = kc * 1024;

    int tid = threadIdx.x;
    if (tid < 128)      // stage u chunk (1024 halves = 128 uint4)
        *(uint4*)&u_s[tid * 8] = *(const uint4*)(u_t + (size_t)bt * 4096 + kbase + tid * 8);
    __syncthreads();    // drains u load; issued BEFORE main prefetch

    int wave = tid >> 6, lane = tid & 63;
    // staging: lane covers row (i*64 + wave*16 + (lane>>2)), swizzled k-slot
    int srow = lane >> 2;                               // 0..15
    int sk = ((lane & 3) ^ ((srow >> 1) & 3)) << 3;     // swizzled k-off (halves)
    const __half* gA = Kh + (size_t)(Xb + wave * 16 + srow) * 4096 + kbase + sk;
    const __half* gB = Qh + (size_t)(Yb + wave * 16 + srow) * 4096 + kbase + sk;

    int wr = (wave >> 1) * 64, wc = (wave & 1) * 64;
    int lrow = lane & 15, kg = lane >> 4;
    int fb = (kg * 16) ^ (((lrow >> 1) & 3) << 4);      // frag read byte in row

    f32x4 acc[4][4];
    f32x4 zero = {0.f, 0.f, 0.f, 0.f};
    #pragma unroll
    for (int m = 0; m < 4; ++m)
        #pragma unroll
        for (int n = 0; n < 4; ++n) acc[m][n] = zero;

    // 4 gl_lds per wave per stage (A i=0,1 ; B i=0,1)
    #define STAGE(s, buf)                                                      \
        do {                                                                   \
            _Pragma("unroll")                                                  \
            for (int i_ = 0; i_ < 2; ++i_) {                                   \
                gl_lds16(gA + (size_t)(i_ * 64) * 4096 + (s) * 32,             \
                         &As[buf][i_ * 64 + wave * 16][0]);                    \
                gl_lds16(gB + (size_t)(i_ * 64) * 4096 + (s) * 32,             \
                         &Bs[buf][i_ * 64 + wave * 16][0]);                    \
            }                                                                  \
        } while (0)

    STAGE(0, 0);
    STAGE(1, 1);

    for (int s = 0; s < 32; ++s) {
        // retire this step's 4 loads (oldest of 8 outstanding)
        if (s < 31) asm volatile("s_waitcnt vmcnt(4)" ::: "memory");
        else        asm volatile("s_waitcnt vmcnt(0)" ::: "memory");
        __builtin_amdgcn_s_barrier();
        __builtin_amdgcn_sched_barrier(0);

        int cur = s & 1;
        uint4 uv = *(const uint4*)&u_s[s * 32 + kg * 8];
        half8 af[4], bf[4];
        #pragma unroll
        for (int m = 0; m < 4; ++m)
            af[m] = mul8(*(const uint4*)((const char*)&As[cur][wr + m * 16 + lrow][0] + fb), uv);
        #pragma unroll
        for (int n = 0; n < 4; ++n)
            bf[n] = *(const half8*)((const char*)&Bs[cur][wc + n * 16 + lrow][0] + fb);
        #pragma unroll
        for (int m = 0; m < 4; ++m)
            #pragma unroll
            for (int n = 0; n < 4; ++n)
                acc[m][n] = __builtin_amdgcn_mfma_f32_16x16x32_f16(af[m], bf[n], acc[m][n], 0, 0, 0);

        // my ds_reads retired + all waves past -> safe to restage buf cur
        asm volatile("s_waitcnt lgkmcnt(0)" ::: "memory");
        __builtin_amdgcn_s_barrier();
        __builtin_amdgcn_sched_barrier(0);
        if (s + 2 < 32) STAGE(s + 2, cur);
    }
    #undef STAGE

    // epilogue: D layout col = lane&15, row = (lane>>4)*4 + reg ; fp16 out
    __half* outp = kvtp + (size_t)kc * KVT_STRIDE + (size_t)bt * 65536;
    int row0 = Xb + wr + kg * 4;
    int col0 = Yb + wc + lrow;
    #pragma unroll
    for (int m = 0; m < 4; ++m)
        #pragma unroll
        for (int n = 0; n < 4; ++n)
            #pragma unroll
            for (int rr = 0; rr < 4; ++rr)
                outp[(size_t)(row0 + m * 16 + rr) * 256 + col0 + n * 16] =
                    __float2half(acc[m][n][rr]);
}

// ---------------------------------------------------------------------------
// Sp[cb][bp][J][n] = sum_{k in 128-chunk cb} clip(Ano[k][n]) * kvt[bp*12+J][k]
// kvt materialized on the fly as f32 sum of KS fp16 partials.
// ---------------------------------------------------------------------------
__global__ __launch_bounds__(256) void s_partial(const float* __restrict__ Ano,
                                                 const __half* __restrict__ kvtp,
                                                 float* __restrict__ Sp)
{
    __shared__ float ano_f[12864];          // 128*100 + pad
    __shared__ float kvt_s[44][128];
    int cb = blockIdx.x;
    int k0 = cb * 128;
    int tid = threadIdx.x;

    {
        const f32x4* src = (const f32x4*)(Ano + (size_t)k0 * 100);
        f32x4* dst = (f32x4*)ano_f;
        for (int i = tid; i < 3200; i += 256) {
            f32x4 f = __builtin_nontemporal_load(src + i);
            f.x = clip1(f.x); f.y = clip1(f.y); f.z = clip1(f.z); f.w = clip1(f.w);
            dst[i] = f;
        }
    }
    {
        for (int idx = tid; idx < 5632; idx += 256) {
            int rI = idx >> 7, k = idx & 127;
            int bpr = rI / 11, Jr = rI - bpr * 11;
            size_t off = (size_t)(bpr * 12 + Jr) * 65536 + k0 + k;
            float v = 0.f;
            #pragma unroll
            for (int c = 0; c < KS; ++c)
                v += __half2float(kvtp[(size_t)c * KVT_STRIDE + off]);
            kvt_s[rI][k] = v;
        }
    }
    __syncthreads();

    int lane = tid & 63;
    int bp = tid >> 6;
    bool has2 = lane < 36;
    float acc0[11], acc1[11];
    #pragma unroll
    for (int J = 0; J < 11; ++J) { acc0[J] = 0.f; acc1[J] = 0.f; }

    for (int k = 0; k < 128; k += 4) {
        f32x4 kv[11];
        #pragma unroll
        for (int J = 0; J < 11; ++J)
            kv[J] = *(const f32x4*)&kvt_s[bp * 11 + J][k];
        #pragma unroll
        for (int kk = 0; kk < 4; ++kk) {
            float a0 = ano_f[(k + kk) * 100 + lane];
            float a1r = ano_f[(k + kk) * 100 + 64 + lane];
            float a1 = has2 ? a1r : 0.f;
            #pragma unroll
            for (int J = 0; J < 11; ++J) {
                acc0[J] += kv[J][kk] * a0;
                acc1[J] += kv[J][kk] * a1;
            }
        }
    }
    float* outb = Sp + ((size_t)cb * 4 + bp) * 1100;
    #pragma unroll
    for (int J = 0; J < 11; ++J) {
        outb[J * 100 + lane] = acc0[J];
        if (has2) outb[J * 100 + 64 + lane] = acc1[J];
    }
}

// Sq[qq][bp*11+J][n] = sum_{cb in quarter qq} Sp[cb][bp][J][n] ; grid 176 x 128
// block 0 also zeroes out[64] (hw accumulates into it afterwards)
__global__ void reduce_s(const float* __restrict__ Sp, float* __restrict__ Sq,
                         float* __restrict__ out)
{
    int bid = blockIdx.x;
    int t = threadIdx.x;
    if (bid == 0 && t < 64) out[t] = 0.f;
    int qq = bid & 3, idx = bid >> 2;       // idx 0..43
    int bp = idx / 11, J = idx - bp * 11;
    if (t >= 100) return;
    float acc = 0.f;
    for (int c = qq * 128; c < qq * 128 + 128; ++c)
        acc += Sp[((size_t)c * 4 + bp) * 1100 + J * 100 + t];
    Sq[(size_t)(qq * 44 + idx) * 100 + t] = acc;
}

// hw[bp][X] = sum_x w[x]*Aoo[X,x]*kvt11[X,x] + sum_n c2[bp][n]*W2[X][n]
// c2 recomputed per block from Sq (LDS); y via atomicAdd(out).
// grid 256 (bp*64+Xg) x 256
__global__ __launch_bounds__(256) void hw_kernel(const float* __restrict__ Aoo,
                                                 const float* __restrict__ wv,
                                                 const __half* __restrict__ kvtp,
                                                 const float* __restrict__ W2p,
                                                 const float* __restrict__ Sq,
                                                 const float* __restrict__ Ann,
                                                 const float* __restrict__ R,
                                                 float* __restrict__ out)
{
    __shared__ float yp[4][16];
    __shared__ float c2s[128];
    int bp = blockIdx.x >> 6, Xg = blockIdx.x & 63;
    int tid = threadIdx.x;

    if (tid < 128) {
        int n = tid;
        float r = 0.f;
        if (n < 100) {
            float S[11];
            #pragma unroll
            for (int J = 0; J < 11; ++J) {
                float s = 0.f;
                #pragma unroll
                for (int qq = 0; qq < 4; ++qq)
                    s += Sq[(size_t)(qq * 44 + bp * 11 + J) * 100 + n];
                S[J] = s;
            }
            float a = Ann[n];
            float seq[10];
            float v = a;
            seq[0] = v;
            #pragma unroll
            for (int s2 = 1; s2 < 10; ++s2) { v = clip1(v * a); seq[s2] = v; }
            r = S[10];
            #pragma unroll
            for (int J = 0; J < 10; ++J)
                r += seq[9 - J] * S[J];
        }
        c2s[n] = r;
    }
    __syncthreads();

    int wave = tid >> 6, lane = tid & 63;
    int X = Xg * 4 + wave;
    size_t base = (size_t)(bp * 12 + 11) * 65536 + (size_t)X * 256;
    const float* ao = Aoo + (size_t)X * 256;
    float red = 0.f;
    #pragma unroll
    for (int qq = 0; qq < 4; ++qq) {
        int xx = qq * 64 + lane;
        float kvv = 0.f;
        #pragma unroll
        for (int c = 0; c < KS; ++c)
            kvv += __half2float(kvtp[(size_t)c * KVT_STRIDE + base + xx]);
        red += wv[xx] * ao[xx] * kvv;
    }
    float w2a = 0.f, w2b = 0.f;
    #pragma unroll
    for (int g = 0; g < 4; ++g) {
        w2a += W2p[((size_t)g * 256 + X) * 100 + lane];
        if (lane < 36) w2b += W2p[((size_t)g * 256 + X) * 100 + 64 + lane];
    }
    red += c2s[lane] * w2a;
    if (lane < 36)
        red += c2s[64 + lane] * w2b;
    #pragma unroll
    for (int off = 32; off; off >>= 1) red += __shfl_xor(red, off);
    // all lanes hold hw[bp][X]
    if (lane < 16) yp[wave][lane] = red * R[((size_t)bp * 256 + X) * 16 + lane];
    __syncthreads();
    if (tid < 16) {
        float s = yp[0][tid] + yp[1][tid] + yp[2][tid] + yp[3][tid];
        atomicAdd(&out[bp * 16 + tid], s);
    }
}

// ---------------------------------------------------------------------------
extern "C" void kernel_launch(void* const* d_in, const int* in_sizes, int n_in,
                              void* d_out, int out_size, void* d_ws, size_t ws_size,
                              hipStream_t stream)
{
    const float* x   = (const float*)d_in[0];
    const float* K   = (const float*)d_in[1];
    const float* Q   = (const float*)d_in[2];
    const float* V   = (const float*)d_in[3];
    const float* Aoo = (const float*)d_in[4];
    const float* Ann = (const float*)d_in[5];
    const float* Aon = (const float*)d_in[6];
    const float* Ano = (const float*)d_in[7];
    const float* wv  = (const float*)d_in[8];
    float* out = (float*)d_out;

    char* ws = (char*)d_ws;
    const size_t o_Qh   = 0;                                  // 2 MB
    const size_t o_Kh   = o_Qh + (size_t)2 * 1024 * 1024;     // 2 MB
    const size_t o_ut   = o_Kh + (size_t)2 * 1024 * 1024;     // 384 KB (pad .5 MB)
    const size_t o_kvtp = o_ut + (size_t)512 * 1024;          // KS*6 MB (fp16)
    const size_t o_Sp   = o_kvtp + (size_t)KS * KVT_STRIDE * 2;
    const size_t o_Sq   = o_Sp + (size_t)512 * 4400 * 4;
    const size_t o_W2   = o_Sq + (size_t)17600 * 4 + 64;      // 4*256*100 f32
    const size_t o_R    = o_W2 + (size_t)102400 * 4;          // 4*256*16 f32

    __half* Qh  = (__half*)(ws + o_Qh);
    __half* Kh  = (__half*)(ws + o_Kh);
    __half* u_t = (__half*)(ws + o_ut);
    __half* kvtp = (__half*)(ws + o_kvtp);
    float* Sp   = (float*)(ws + o_Sp);
    float* Sq   = (float*)(ws + o_Sq);
    float* W2p  = (float*)(ws + o_W2);
    float* R    = (float*)(ws + o_R);

    hipLaunchKernelGGL(prep_kernel, dim3(2864), dim3(256), 0, stream,
                       K, Q, x, Aon, wv, V, Kh, Qh, u_t, W2p, R);
    hipLaunchKernelGGL(gemm_kvt,    dim3(768),  dim3(256), 0, stream, Kh, Qh, u_t, kvtp);
    hipLaunchKernelGGL(s_partial,   dim3(512),  dim3(256), 0, stream, Ano, kvtp, Sp);
    hipLaunchKernelGGL(reduce_s,    dim3(176),  dim3(128), 0, stream, Sp, Sq, out);
    hipLaunchKernelGGL(hw_kernel,   dim3(256),  dim3(256), 0, stream,
                       Aoo, wv, kvtp, W2p, Sq, Ann, R, out);
}

// Round 11
// 104.970 us; speedup vs baseline: 1.5925x; 1.0017x over previous
//
#include <hip/hip_runtime.h>
#include <hip/hip_fp16.h>

// ---------------------------------------------------------------------------
// NL=16, NS=256, NE=100, B=2, P=2, T=12
// x:(2,2,12,16,256) K/Q/V:(256,256,16) Aoo:(256,256) Ann:(100,)
// Aon/Ano:(256,256,100) w:(256,)  out:(2,2,1,16)=64 fp32
// kvt[bt][X][Y] = sum_j Kh[X,j]*u[bt,j]*Qh[Y,j],  j = x*16+c  (K=4096)
// ---------------------------------------------------------------------------

using f32x4 = __attribute__((ext_vector_type(4))) float;
using half8 = __attribute__((ext_vector_type(8))) _Float16;
using half4 = __attribute__((ext_vector_type(4))) _Float16;

#define KVT_STRIDE 3145728ull    // 48*65536 halves per K-chunk partial
#define KS 4

__device__ inline float clip1(float v) { return fminf(fmaxf(v, -1.f), 1.f); }

__device__ inline half8 mul8(uint4 a, uint4 b) {
    half8 x = __builtin_bit_cast(half8, a);
    half8 y = __builtin_bit_cast(half8, b);
    return x * y;                          // v_pk_mul_f16 x4
}

__device__ __forceinline__ void gl_lds16(const void* g, void* l) {
    __builtin_amdgcn_global_load_lds(
        (const __attribute__((address_space(1))) void*)g,
        (__attribute__((address_space(3))) void*)l, 16, 0, 0);
}

// ---------------------------------------------------------------------------
// Fused prep: [0,2048) K/Q->fp16 ; [2048,2096) u_t ; [2096,2608) W2p (4 grp);
// [2608,2864) R.  grid 2864 x 256
// ---------------------------------------------------------------------------
__global__ void prep_kernel(const float* __restrict__ K, const float* __restrict__ Q,
                            const float* __restrict__ xin,
                            const float* __restrict__ Aon, const float* __restrict__ wv,
                            const float* __restrict__ V,
                            __half* __restrict__ Kh, __half* __restrict__ Qh,
                            __half* __restrict__ u_t,
                            float* __restrict__ W2p, float* __restrict__ R)
{
    int b = blockIdx.x, t = threadIdx.x;
    if (b < 2048) {
        bool isK = (b < 1024);
        int bb = isK ? b : b - 1024;
        int i = bb * 1024 + t * 4;
        const float4 f = ((const float4*)(isK ? K : Q))[i >> 2];
        half4 v = { (_Float16)f.x, (_Float16)f.y, (_Float16)f.z, (_Float16)f.w };
        *(half4*)((isK ? Kh : Qh) + i) = v;
    } else if (b < 2096) {
        int bt = b - 2048;                    // 0..47
        const float* src = xin + (size_t)bt * 4096;
        int xx = t;                           // 0..255
        half8 lo, hi;
        #pragma unroll
        for (int c = 0; c < 8; ++c)  lo[c] = (_Float16)src[c * 256 + xx];
        #pragma unroll
        for (int c = 0; c < 8; ++c)  hi[c] = (_Float16)src[(c + 8) * 256 + xx];
        half8* dst = (half8*)(u_t + (size_t)bt * 4096 + xx * 16);
        dst[0] = lo; dst[1] = hi;
    } else if (b < 2608) {
        // W2p[g][X][n] = sum_{b in g*64..+64} w[b]*clip(Aon[X,b,n])
        int idx = b - 2096;                   // 0..511
        int X = idx >> 1, h = idx & 1;
        int g = h * 2 + (t >> 7), n = t & 127;
        if (n < 100) {
            const float* base = Aon + (size_t)X * 25600 + (size_t)g * 6400 + n;
            float acc = 0.f;
            for (int bb = 0; bb < 64; ++bb)
                acc += wv[g * 64 + bb] * clip1(__builtin_nontemporal_load(base + (size_t)bb * 100));
            W2p[((size_t)g * 256 + X) * 100 + n] = acc;
        }
    } else {
        // R[bp][X][c] = sum_x xlast[bp][c][x] * V[X][x*16+c]
        __shared__ float vrow[4096];
        int X = b - 2608;                     // 0..255
        {
            const float4* src = (const float4*)(V + (size_t)X * 4096);
            float4* dst = (float4*)vrow;
            for (int i = t; i < 1024; i += 256) dst[i] = src[i];
        }
        __syncthreads();
        int bp = t >> 6, c = (t >> 2) & 15, g = t & 3;
        const float* xl = xin + ((size_t)(bp * 12) + 11) * 4096 + c * 256;
        float p = 0.f;
        #pragma unroll 4
        for (int x = g * 64; x < g * 64 + 64; ++x)
            p += xl[x] * vrow[x * 16 + c];
        p += __shfl_xor(p, 1);
        p += __shfl_xor(p, 2);
        if (g == 0) R[((size_t)bp * 256 + X) * 16 + c] = p;
    }
}

// ---------------------------------------------------------------------------
// GEMM: 128x128 tile, K-chunk Kc=1024 (KS=4), BK=32, double-buffered LDS via
// global_load_lds dwordx4, 8-group XOR swizzle (kslot ^ (row>>1)&3, via
// pre-swizzled global source). Counted-vmcnt 2-ahead; LDS 34 KB -> 4 blk/CU.
// fp16 partial output.
// ---------------------------------------------------------------------------
__global__ __launch_bounds__(256, 4) void gemm_kvt(
    const __half* __restrict__ Kh, const __half* __restrict__ Qh,
    const __half* __restrict__ u_t, __half* __restrict__ kvtp)
{
    __shared__ __half As[2][128][32];   // 8 KB per buf
    __shared__ __half Bs[2][128][32];
    __shared__ __half u_s[1024];        // 2 KB

    int bid = blockIdx.x;
    int work = (bid & 7) * 96 + (bid >> 3);    // XCD x gets contiguous works
    int kc = work / 192;
    int rem = work - kc * 192;
    int tile = rem / 48;
    int bt = rem - tile * 48;
    int Xb = (tile >> 1) * 128, Yb = (tile & 1) * 128;
    int kbase = kc * 1024;

    int tid = threadIdx.x;
    if (tid < 128)      // stage u chunk (1024 halves = 128 uint4)
        *(uint4*)&u_s[tid * 8] = *(const uint4*)(u_t + (size_t)bt * 4096 + kbase + tid * 8);
    __syncthreads();    // drains u load; issued BEFORE main prefetch

    int wave = tid >> 6, lane = tid & 63;
    // staging: lane covers row (i*64 + wave*16 + (lane>>2)), swizzled k-slot
    int srow = lane >> 2;                               // 0..15
    int sk = ((lane & 3) ^ ((srow >> 1) & 3)) << 3;     // swizzled k-off (halves)
    const __half* gA = Kh + (size_t)(Xb + wave * 16 + srow) * 4096 + kbase + sk;
    const __half* gB = Qh + (size_t)(Yb + wave * 16 + srow) * 4096 + kbase + sk;

    int wr = (wave >> 1) * 64, wc = (wave & 1) * 64;
    int lrow = lane & 15, kg = lane >> 4;
    int fb = (kg * 16) ^ (((lrow >> 1) & 3) << 4);      // frag read byte in row

    f32x4 acc[4][4];
    f32x4 zero = {0.f, 0.f, 0.f, 0.f};
    #pragma unroll
    for (int m = 0; m < 4; ++m)
        #pragma unroll
        for (int n = 0; n < 4; ++n) acc[m][n] = zero;

    // 4 gl_lds per wave per stage (A i=0,1 ; B i=0,1)
    #define STAGE(s, buf)                                                      \
        do {                                                                   \
            _Pragma("unroll")                                                  \
            for (int i_ = 0; i_ < 2; ++i_) {                                   \
                gl_lds16(gA + (size_t)(i_ * 64) * 4096 + (s) * 32,             \
                         &As[buf][i_ * 64 + wave * 16][0]);                    \
                gl_lds16(gB + (size_t)(i_ * 64) * 4096 + (s) * 32,             \
                         &Bs[buf][i_ * 64 + wave * 16][0]);                    \
            }                                                                  \
        } while (0)

    STAGE(0, 0);
    STAGE(1, 1);

    for (int s = 0; s < 32; ++s) {
        // retire this step's 4 loads (oldest of 8 outstanding)
        if (s < 31) asm volatile("s_waitcnt vmcnt(4)" ::: "memory");
        else        asm volatile("s_waitcnt vmcnt(0)" ::: "memory");
        __builtin_amdgcn_s_barrier();
        __builtin_amdgcn_sched_barrier(0);

        int cur = s & 1;
        uint4 uv = *(const uint4*)&u_s[s * 32 + kg * 8];
        half8 af[4], bf[4];
        #pragma unroll
        for (int m = 0; m < 4; ++m)
            af[m] = mul8(*(const uint4*)((const char*)&As[cur][wr + m * 16 + lrow][0] + fb), uv);
        #pragma unroll
        for (int n = 0; n < 4; ++n)
            bf[n] = *(const half8*)((const char*)&Bs[cur][wc + n * 16 + lrow][0] + fb);
        #pragma unroll
        for (int m = 0; m < 4; ++m)
            #pragma unroll
            for (int n = 0; n < 4; ++n)
                acc[m][n] = __builtin_amdgcn_mfma_f32_16x16x32_f16(af[m], bf[n], acc[m][n], 0, 0, 0);

        // my ds_reads retired + all waves past -> safe to restage buf cur
        asm volatile("s_waitcnt lgkmcnt(0)" ::: "memory");
        __builtin_amdgcn_s_barrier();
        __builtin_amdgcn_sched_barrier(0);
        if (s + 2 < 32) STAGE(s + 2, cur);
    }
    #undef STAGE

    // epilogue: D layout col = lane&15, row = (lane>>4)*4 + reg ; fp16 out
    __half* outp = kvtp + (size_t)kc * KVT_STRIDE + (size_t)bt * 65536;
    int row0 = Xb + wr + kg * 4;
    int col0 = Yb + wc + lrow;
    #pragma unroll
    for (int m = 0; m < 4; ++m)
        #pragma unroll
        for (int n = 0; n < 4; ++n)
            #pragma unroll
            for (int rr = 0; rr < 4; ++rr)
                outp[(size_t)(row0 + m * 16 + rr) * 256 + col0 + n * 16] =
                    __float2half(acc[m][n][rr]);
}

// ---------------------------------------------------------------------------
// Sp[cb][bp][J][n] = sum_{k in 128-chunk cb} clip(Ano[k][n]) * kvt[bp*12+J][k]
// kvt materialized on the fly as f32 sum of KS fp16 partials.
// ---------------------------------------------------------------------------
__global__ __launch_bounds__(256) void s_partial(const float* __restrict__ Ano,
                                                 const __half* __restrict__ kvtp,
                                                 float* __restrict__ Sp)
{
    __shared__ float ano_f[12864];          // 128*100 + pad
    __shared__ float kvt_s[44][128];
    int cb = blockIdx.x;
    int k0 = cb * 128;
    int tid = threadIdx.x;

    {
        const f32x4* src = (const f32x4*)(Ano + (size_t)k0 * 100);
        f32x4* dst = (f32x4*)ano_f;
        for (int i = tid; i < 3200; i += 256) {
            f32x4 f = __builtin_nontemporal_load(src + i);
            f.x = clip1(f.x); f.y = clip1(f.y); f.z = clip1(f.z); f.w = clip1(f.w);
            dst[i] = f;
        }
    }
    {
        for (int idx = tid; idx < 5632; idx += 256) {
            int rI = idx >> 7, k = idx & 127;
            int bpr = rI / 11, Jr = rI - bpr * 11;
            size_t off = (size_t)(bpr * 12 + Jr) * 65536 + k0 + k;
            float v = 0.f;
            #pragma unroll
            for (int c = 0; c < KS; ++c)
                v += __half2float(kvtp[(size_t)c * KVT_STRIDE + off]);
            kvt_s[rI][k] = v;
        }
    }
    __syncthreads();

    int lane = tid & 63;
    int bp = tid >> 6;
    bool has2 = lane < 36;
    float acc0[11], acc1[11];
    #pragma unroll
    for (int J = 0; J < 11; ++J) { acc0[J] = 0.f; acc1[J] = 0.f; }

    for (int k = 0; k < 128; k += 4) {
        f32x4 kv[11];
        #pragma unroll
        for (int J = 0; J < 11; ++J)
            kv[J] = *(const f32x4*)&kvt_s[bp * 11 + J][k];
        #pragma unroll
        for (int kk = 0; kk < 4; ++kk) {
            float a0 = ano_f[(k + kk) * 100 + lane];
            float a1r = ano_f[(k + kk) * 100 + 64 + lane];
            float a1 = has2 ? a1r : 0.f;
            #pragma unroll
            for (int J = 0; J < 11; ++J) {
                acc0[J] += kv[J][kk] * a0;
                acc1[J] += kv[J][kk] * a1;
            }
        }
    }
    float* outb = Sp + ((size_t)cb * 4 + bp) * 1100;
    #pragma unroll
    for (int J = 0; J < 11; ++J) {
        outb[J * 100 + lane] = acc0[J];
        if (has2) outb[J * 100 + 64 + lane] = acc1[J];
    }
}

// Sq[qq][bp*11+J][n] = sum_{cb in quarter qq} Sp[cb][bp][J][n] ; grid 176 x 128
// block 0 also zeroes out[64] (hw accumulates into it afterwards)
__global__ void reduce_s(const float* __restrict__ Sp, float* __restrict__ Sq,
                         float* __restrict__ out)
{
    int bid = blockIdx.x;
    int t = threadIdx.x;
    if (bid == 0 && t < 64) out[t] = 0.f;
    int qq = bid & 3, idx = bid >> 2;       // idx 0..43
    int bp = idx / 11, J = idx - bp * 11;
    if (t >= 100) return;
    float acc = 0.f;
    for (int c = qq * 128; c < qq * 128 + 128; ++c)
        acc += Sp[((size_t)c * 4 + bp) * 1100 + J * 100 + t];
    Sq[(size_t)(qq * 44 + idx) * 100 + t] = acc;
}

// hw[bp][X] = sum_x w[x]*Aoo[X,x]*kvt11[X,x] + sum_n c2[bp][n]*W2[X][n]
// c2 recomputed per block from Sq (LDS); y via atomicAdd(out).
// grid 256 (bp*64+Xg) x 256
__global__ __launch_bounds__(256) void hw_kernel(const float* __restrict__ Aoo,
                                                 const float* __restrict__ wv,
                                                 const __half* __restrict__ kvtp,
                                                 const float* __restrict__ W2p,
                                                 const float* __restrict__ Sq,
                                                 const float* __restrict__ Ann,
                                                 const float* __restrict__ R,
                                                 float* __restrict__ out)
{
    __shared__ float yp[4][16];
    __shared__ float c2s[128];
    int bp = blockIdx.x >> 6, Xg = blockIdx.x & 63;
    int tid = threadIdx.x;

    if (tid < 128) {
        int n = tid;
        float r = 0.f;
        if (n < 100) {
            float S[11];
            #pragma unroll
            for (int J = 0; J < 11; ++J) {
                float s = 0.f;
                #pragma unroll
                for (int qq = 0; qq < 4; ++qq)
                    s += Sq[(size_t)(qq * 44 + bp * 11 + J) * 100 + n];
                S[J] = s;
            }
            float a = Ann[n];
            float seq[10];
            float v = a;
            seq[0] = v;
            #pragma unroll
            for (int s2 = 1; s2 < 10; ++s2) { v = clip1(v * a); seq[s2] = v; }
            r = S[10];
            #pragma unroll
            for (int J = 0; J < 10; ++J)
                r += seq[9 - J] * S[J];
        }
        c2s[n] = r;
    }
    __syncthreads();

    int wave = tid >> 6, lane = tid & 63;
    int X = Xg * 4 + wave;
    size_t base = (size_t)(bp * 12 + 11) * 65536 + (size_t)X * 256;
    const float* ao = Aoo + (size_t)X * 256;
    float red = 0.f;
    #pragma unroll
    for (int qq = 0; qq < 4; ++qq) {
        int xx = qq * 64 + lane;
        float kvv = 0.f;
        #pragma unroll
        for (int c = 0; c < KS; ++c)
            kvv += __half2float(kvtp[(size_t)c * KVT_STRIDE + base + xx]);
        red += wv[xx] * ao[xx] * kvv;
    }
    float w2a = 0.f, w2b = 0.f;
    #pragma unroll
    for (int g = 0; g < 4; ++g) {
        w2a += W2p[((size_t)g * 256 + X) * 100 + lane];
        if (lane < 36) w2b += W2p[((size_t)g * 256 + X) * 100 + 64 + lane];
    }
    red += c2s[lane] * w2a;
    if (lane < 36)
        red += c2s[64 + lane] * w2b;
    #pragma unroll
    for (int off = 32; off; off >>= 1) red += __shfl_xor(red, off);
    // all lanes hold hw[bp][X]
    if (lane < 16) yp[wave][lane] = red * R[((size_t)bp * 256 + X) * 16 + lane];
    __syncthreads();
    if (tid < 16) {
        float s = yp[0][tid] + yp[1][tid] + yp[2][tid] + yp[3][tid];
        atomicAdd(&out[bp * 16 + tid], s);
    }
}

// ---------------------------------------------------------------------------
extern "C" void kernel_launch(void* const* d_in, const int* in_sizes, int n_in,
                              void* d_out, int out_size, void* d_ws, size_t ws_size,
                              hipStream_t stream)
{
    const float* x   = (const float*)d_in[0];
    const float* K   = (const float*)d_in[1];
    const float* Q   = (const float*)d_in[2];
    const float* V   = (const float*)d_in[3];
    const float* Aoo = (const float*)d_in[4];
    const float* Ann = (const float*)d_in[5];
    const float* Aon = (const float*)d_in[6];
    const float* Ano = (const float*)d_in[7];
    const float* wv  = (const float*)d_in[8];
    float* out = (float*)d_out;

    char* ws = (char*)d_ws;
    const size_t o_Qh   = 0;                                  // 2 MB
    const size_t o_Kh   = o_Qh + (size_t)2 * 1024 * 1024;     // 2 MB
    const size_t o_ut   = o_Kh + (size_t)2 * 1024 * 1024;     // 384 KB (pad .5 MB)
    const size_t o_kvtp = o_ut + (size_t)512 * 1024;          // KS*6 MB (fp16)
    const size_t o_Sp   = o_kvtp + (size_t)KS * KVT_STRIDE * 2;
    const size_t o_Sq   = o_Sp + (size_t)512 * 4400 * 4;
    const size_t o_W2   = o_Sq + (size_t)17600 * 4 + 64;      // 4*256*100 f32
    const size_t o_R    = o_W2 + (size_t)102400 * 4;          // 4*256*16 f32

    __half* Qh  = (__half*)(ws + o_Qh);
    __half* Kh  = (__half*)(ws + o_Kh);
    __half* u_t = (__half*)(ws + o_ut);
    __half* kvtp = (__half*)(ws + o_kvtp);
    float* Sp   = (float*)(ws + o_Sp);
    float* Sq   = (float*)(ws + o_Sq);
    float* W2p  = (float*)(ws + o_W2);
    float* R    = (float*)(ws + o_R);

    hipLaunchKernelGGL(prep_kernel, dim3(2864), dim3(256), 0, stream,
                       K, Q, x, Aon, wv, V, Kh, Qh, u_t, W2p, R);
    hipLaunchKernelGGL(gemm_kvt,    dim3(768),  dim3(256), 0, stream, Kh, Qh, u_t, kvtp);
    hipLaunchKernelGGL(s_partial,   dim3(512),  dim3(256), 0, stream, Ano, kvtp, Sp);
    hipLaunchKernelGGL(reduce_s,    dim3(176),  dim3(128), 0, stream, Sp, Sq, out);
    hipLaunchKernelGGL(hw_kernel,   dim3(256),  dim3(256), 0, stream,
                       Aoo, wv, kvtp, W2p, Sq, Ann, R, out);
}

// Round 12
// 104.172 us; speedup vs baseline: 1.6047x; 1.0077x over previous
//
#include <hip/hip_runtime.h>
#include <hip/hip_fp16.h>

// ---------------------------------------------------------------------------
// NL=16, NS=256, NE=100, B=2, P=2, T=12
// x:(2,2,12,16,256) K/Q/V:(256,256,16) Aoo:(256,256) Ann:(100,)
// Aon/Ano:(256,256,100) w:(256,)  out:(2,2,1,16)=64 fp32
// kvt[bt][X][Y] = sum_j Kh[X,j]*u[bt,j]*Qh[Y,j],  j = x*16+c  (K=4096)
// ---------------------------------------------------------------------------

using f32x4 = __attribute__((ext_vector_type(4))) float;
using half8 = __attribute__((ext_vector_type(8))) _Float16;
using half4 = __attribute__((ext_vector_type(4))) _Float16;

#define KVT_STRIDE 3145728ull    // 48*65536 halves per K-chunk partial
#define KS 4

__device__ inline float clip1(float v) { return fminf(fmaxf(v, -1.f), 1.f); }

__device__ inline half8 mul8(uint4 a, uint4 b) {
    half8 x = __builtin_bit_cast(half8, a);
    half8 y = __builtin_bit_cast(half8, b);
    return x * y;                          // v_pk_mul_f16 x4
}

__device__ __forceinline__ void gl_lds16(const void* g, void* l) {
    __builtin_amdgcn_global_load_lds(
        (const __attribute__((address_space(1))) void*)g,
        (__attribute__((address_space(3))) void*)l, 16, 0, 0);
}

// ---------------------------------------------------------------------------
// Fused prep: [0,2048) K/Q->fp16 ; [2048,2096) u_t ; [2096,2608) W2p (4 grp);
// [2608,2864) R.  grid 2864 x 256
// ---------------------------------------------------------------------------
__global__ void prep_kernel(const float* __restrict__ K, const float* __restrict__ Q,
                            const float* __restrict__ xin,
                            const float* __restrict__ Aon, const float* __restrict__ wv,
                            const float* __restrict__ V,
                            __half* __restrict__ Kh, __half* __restrict__ Qh,
                            __half* __restrict__ u_t,
                            float* __restrict__ W2p, float* __restrict__ R)
{
    int b = blockIdx.x, t = threadIdx.x;
    if (b < 2048) {
        bool isK = (b < 1024);
        int bb = isK ? b : b - 1024;
        int i = bb * 1024 + t * 4;
        const float4 f = ((const float4*)(isK ? K : Q))[i >> 2];
        half4 v = { (_Float16)f.x, (_Float16)f.y, (_Float16)f.z, (_Float16)f.w };
        *(half4*)((isK ? Kh : Qh) + i) = v;
    } else if (b < 2096) {
        int bt = b - 2048;                    // 0..47
        const float* src = xin + (size_t)bt * 4096;
        int xx = t;                           // 0..255
        half8 lo, hi;
        #pragma unroll
        for (int c = 0; c < 8; ++c)  lo[c] = (_Float16)src[c * 256 + xx];
        #pragma unroll
        for (int c = 0; c < 8; ++c)  hi[c] = (_Float16)src[(c + 8) * 256 + xx];
        half8* dst = (half8*)(u_t + (size_t)bt * 4096 + xx * 16);
        dst[0] = lo; dst[1] = hi;
    } else if (b < 2608) {
        // W2p[g][X][n] = sum_{b in g*64..+64} w[b]*clip(Aon[X,b,n])
        int idx = b - 2096;                   // 0..511
        int X = idx >> 1, h = idx & 1;
        int g = h * 2 + (t >> 7), n = t & 127;
        if (n < 100) {
            const float* base = Aon + (size_t)X * 25600 + (size_t)g * 6400 + n;
            float acc = 0.f;
            for (int bb = 0; bb < 64; ++bb)
                acc += wv[g * 64 + bb] * clip1(__builtin_nontemporal_load(base + (size_t)bb * 100));
            W2p[((size_t)g * 256 + X) * 100 + n] = acc;
        }
    } else {
        // R[bp][X][c] = sum_x xlast[bp][c][x] * V[X][x*16+c]
        __shared__ float vrow[4096];
        int X = b - 2608;                     // 0..255
        {
            const float4* src = (const float4*)(V + (size_t)X * 4096);
            float4* dst = (float4*)vrow;
            for (int i = t; i < 1024; i += 256) dst[i] = src[i];
        }
        __syncthreads();
        int bp = t >> 6, c = (t >> 2) & 15, g = t & 3;
        const float* xl = xin + ((size_t)(bp * 12) + 11) * 4096 + c * 256;
        float p = 0.f;
        #pragma unroll 4
        for (int x = g * 64; x < g * 64 + 64; ++x)
            p += xl[x] * vrow[x * 16 + c];
        p += __shfl_xor(p, 1);
        p += __shfl_xor(p, 2);
        if (g == 0) R[((size_t)bp * 256 + X) * 16 + c] = p;
    }
}

// ---------------------------------------------------------------------------
// GEMM: 128x128 tile, Kc=1024 (KS=4), BK=32. A: reg-staged, u-scaled ONCE,
// swizzled ds_write. B: gl_lds DMA with pre-swizzled source. Double-buffered,
// counted-vmcnt (B-dma only; A-reg deps are compiler-tracked). 4 blk/CU.
// fp16 partial output.
// ---------------------------------------------------------------------------
__global__ __launch_bounds__(256, 4) void gemm_kvt(
    const __half* __restrict__ Kh, const __half* __restrict__ Qh,
    const __half* __restrict__ u_t, __half* __restrict__ kvtp)
{
    __shared__ __half As[2][128][32];   // 8 KB per buf
    __shared__ __half Bs[2][128][32];
    __shared__ __half u_s[1024];        // 2 KB

    int bid = blockIdx.x;
    int work = (bid & 7) * 96 + (bid >> 3);    // XCD x gets contiguous works
    int kc = work / 192;
    int rem = work - kc * 192;
    int tile = rem / 48;
    int bt = rem - tile * 48;
    int Xb = (tile >> 1) * 128, Yb = (tile & 1) * 128;
    int kbase = kc * 1024;

    int tid = threadIdx.x;
    if (tid < 128)      // stage u chunk (1024 halves = 128 uint4)
        *(uint4*)&u_s[tid * 8] = *(const uint4*)(u_t + (size_t)bt * 4096 + kbase + tid * 8);
    __syncthreads();    // drains u load

    int wave = tid >> 6, lane = tid & 63;

    // ---- A staging geometry: thread -> (row, 2 slots), swizzled ds_write ----
    int arow = tid >> 1;                            // 0..127
    int apair = (tid & 1) * 2;                      // slot base 0 or 2
    const __half* gA = Kh + (size_t)(Xb + arow) * 4096 + kbase + apair * 8;
    int aswz = (arow >> 1) & 3;
    int asb0 = ((apair + 0) ^ aswz) << 4;           // byte offsets in row
    int asb1 = ((apair + 1) ^ aswz) << 4;

    // ---- B staging geometry (gl_lds, pre-swizzled global source) ----
    int srow = lane >> 2;                           // 0..15
    int sk = ((lane & 3) ^ ((srow >> 1) & 3)) << 3; // swizzled k-off (halves)
    const __half* gB = Qh + (size_t)(Yb + wave * 16 + srow) * 4096 + kbase + sk;

    int wr = (wave >> 1) * 64, wc = (wave & 1) * 64;
    int lrow = lane & 15, kg = lane >> 4;
    int fb = (kg * 16) ^ (((lrow >> 1) & 3) << 4);  // frag read byte in row

    f32x4 acc[4][4];
    f32x4 zero = {0.f, 0.f, 0.f, 0.f};
    #pragma unroll
    for (int m = 0; m < 4; ++m)
        #pragma unroll
        for (int n = 0; n < 4; ++n) acc[m][n] = zero;

    #define ISSUE_B(s, buf)                                                    \
        do {                                                                   \
            _Pragma("unroll")                                                  \
            for (int i_ = 0; i_ < 2; ++i_)                                     \
                gl_lds16(gB + (size_t)(i_ * 64) * 4096 + (s) * 32,             \
                         &Bs[buf][i_ * 64 + wave * 16][0]);                    \
        } while (0)

    #define WRITE_A(s, r0, r1, buf)                                            \
        do {                                                                   \
            uint4 uv0 = *(const uint4*)&u_s[(s) * 32 + apair * 8];             \
            uint4 uv1 = *(const uint4*)&u_s[(s) * 32 + apair * 8 + 8];         \
            *(half8*)((char*)&As[buf][arow][0] + asb0) = mul8(r0, uv0);        \
            *(half8*)((char*)&As[buf][arow][0] + asb1) = mul8(r1, uv1);        \
        } while (0)

    // compute phase: pure ds_read + MFMA (A already scaled in LDS)
    #define COMPUTE(cur)                                                       \
        do {                                                                   \
            half8 af[4], bf[4];                                                \
            _Pragma("unroll")                                                  \
            for (int m = 0; m < 4; ++m)                                        \
                af[m] = *(const half8*)((const char*)&As[cur][wr + m * 16 + lrow][0] + fb); \
            _Pragma("unroll")                                                  \
            for (int n = 0; n < 4; ++n)                                        \
                bf[n] = *(const half8*)((const char*)&Bs[cur][wc + n * 16 + lrow][0] + fb); \
            _Pragma("unroll")                                                  \
            for (int m = 0; m < 4; ++m)                                        \
                _Pragma("unroll")                                              \
                for (int n = 0; n < 4; ++n)                                    \
                    acc[m][n] = __builtin_amdgcn_mfma_f32_16x16x32_f16(af[m], bf[n], acc[m][n], 0, 0, 0); \
        } while (0)

    // one pipeline step: barrier1 -> compute -> barrier2 -> window
    #define STEP(s, c0, c1, i0, i1, cur)                                       \
        do {                                                                   \
            if ((s) < 31) asm volatile("s_waitcnt vmcnt(4) lgkmcnt(0)" ::: "memory"); \
            else          asm volatile("s_waitcnt vmcnt(0) lgkmcnt(0)" ::: "memory"); \
            __builtin_amdgcn_s_barrier();                                      \
            __builtin_amdgcn_sched_barrier(0);                                 \
            COMPUTE(cur);                                                      \
            asm volatile("s_waitcnt lgkmcnt(0)" ::: "memory");                 \
            __builtin_amdgcn_s_barrier();                                      \
            __builtin_amdgcn_sched_barrier(0);                                 \
            if ((s) + 2 < 32) {                                                \
                const __half* a_ = gA + ((s) + 2) * 32;                        \
                i0 = *(const uint4*)a_;                                        \
                i1 = *(const uint4*)(a_ + 8);                                  \
                ISSUE_B((s) + 2, cur);                                         \
            }                                                                  \
            if ((s) + 1 < 32) WRITE_A((s) + 1, c0, c1, (cur) ^ 1);             \
        } while (0)

    // prologue: A(0)->P set, B(0); A(1)->C set, B(1); write A(0) to bufA0
    uint4 aP0, aP1, aC0, aC1;
    aP0 = *(const uint4*)gA;
    aP1 = *(const uint4*)(gA + 8);
    ISSUE_B(0, 0);
    aC0 = *(const uint4*)(gA + 32);
    aC1 = *(const uint4*)(gA + 40);
    ISSUE_B(1, 1);
    WRITE_A(0, aP0, aP1, 0);           // compiler inserts vmcnt for aP deps

    #pragma unroll
    for (int s = 0; s < 32; s += 2) {
        STEP(s,     aC0, aC1, aP0, aP1, 0);   // consume A(s+1)=C, issue A(s+2)->P
        STEP(s + 1, aP0, aP1, aC0, aC1, 1);   // consume A(s+2)=P, issue A(s+3)->C
    }
    #undef STEP
    #undef COMPUTE
    #undef WRITE_A
    #undef ISSUE_B

    // epilogue: D layout col = lane&15, row = (lane>>4)*4 + reg ; fp16 out
    __half* outp = kvtp + (size_t)kc * KVT_STRIDE + (size_t)bt * 65536;
    int row0 = Xb + wr + kg * 4;
    int col0 = Yb + wc + lrow;
    #pragma unroll
    for (int m = 0; m < 4; ++m)
        #pragma unroll
        for (int n = 0; n < 4; ++n)
            #pragma unroll
            for (int rr = 0; rr < 4; ++rr)
                outp[(size_t)(row0 + m * 16 + rr) * 256 + col0 + n * 16] =
                    __float2half(acc[m][n][rr]);
}

// ---------------------------------------------------------------------------
// Sp[cb][bp][J][n] = sum_{k in 128-chunk cb} clip(Ano[k][n]) * kvt[bp*12+J][k]
// kvt materialized on the fly as f32 sum of KS fp16 partials.
// ---------------------------------------------------------------------------
__global__ __launch_bounds__(256) void s_partial(const float* __restrict__ Ano,
                                                 const __half* __restrict__ kvtp,
                                                 float* __restrict__ Sp)
{
    __shared__ float ano_f[12864];          // 128*100 + pad
    __shared__ float kvt_s[44][128];
    int cb = blockIdx.x;
    int k0 = cb * 128;
    int tid = threadIdx.x;

    {
        const f32x4* src = (const f32x4*)(Ano + (size_t)k0 * 100);
        f32x4* dst = (f32x4*)ano_f;
        for (int i = tid; i < 3200; i += 256) {
            f32x4 f = __builtin_nontemporal_load(src + i);
            f.x = clip1(f.x); f.y = clip1(f.y); f.z = clip1(f.z); f.w = clip1(f.w);
            dst[i] = f;
        }
    }
    {
        for (int idx = tid; idx < 5632; idx += 256) {
            int rI = idx >> 7, k = idx & 127;
            int bpr = rI / 11, Jr = rI - bpr * 11;
            size_t off = (size_t)(bpr * 12 + Jr) * 65536 + k0 + k;
            float v = 0.f;
            #pragma unroll
            for (int c = 0; c < KS; ++c)
                v += __half2float(kvtp[(size_t)c * KVT_STRIDE + off]);
            kvt_s[rI][k] = v;
        }
    }
    __syncthreads();

    int lane = tid & 63;
    int bp = tid >> 6;
    bool has2 = lane < 36;
    float acc0[11], acc1[11];
    #pragma unroll
    for (int J = 0; J < 11; ++J) { acc0[J] = 0.f; acc1[J] = 0.f; }

    for (int k = 0; k < 128; k += 4) {
        f32x4 kv[11];
        #pragma unroll
        for (int J = 0; J < 11; ++J)
            kv[J] = *(const f32x4*)&kvt_s[bp * 11 + J][k];
        #pragma unroll
        for (int kk = 0; kk < 4; ++kk) {
            float a0 = ano_f[(k + kk) * 100 + lane];
            float a1r = ano_f[(k + kk) * 100 + 64 + lane];
            float a1 = has2 ? a1r : 0.f;
            #pragma unroll
            for (int J = 0; J < 11; ++J) {
                acc0[J] += kv[J][kk] * a0;
                acc1[J] += kv[J][kk] * a1;
            }
        }
    }
    float* outb = Sp + ((size_t)cb * 4 + bp) * 1100;
    #pragma unroll
    for (int J = 0; J < 11; ++J) {
        outb[J * 100 + lane] = acc0[J];
        if (has2) outb[J * 100 + 64 + lane] = acc1[J];
    }
}

// Sq[qq][bp*11+J][n] = sum_{cb in quarter qq} Sp[cb][bp][J][n] ; grid 176 x 128
// block 0 also zeroes out[64] (hw accumulates into it afterwards)
__global__ void reduce_s(const float* __restrict__ Sp, float* __restrict__ Sq,
                         float* __restrict__ out)
{
    int bid = blockIdx.x;
    int t = threadIdx.x;
    if (bid == 0 && t < 64) out[t] = 0.f;
    int qq = bid & 3, idx = bid >> 2;       // idx 0..43
    int bp = idx / 11, J = idx - bp * 11;
    if (t >= 100) return;
    float acc = 0.f;
    for (int c = qq * 128; c < qq * 128 + 128; ++c)
        acc += Sp[((size_t)c * 4 + bp) * 1100 + J * 100 + t];
    Sq[(size_t)(qq * 44 + idx) * 100 + t] = acc;
}

// hw[bp][X] = sum_x w[x]*Aoo[X,x]*kvt11[X,x] + sum_n c2[bp][n]*W2[X][n]
// c2 recomputed per block from Sq (LDS); y via atomicAdd(out).
// grid 256 (bp*64+Xg) x 256
__global__ __launch_bounds__(256) void hw_kernel(const float* __restrict__ Aoo,
                                                 const float* __restrict__ wv,
                                                 const __half* __restrict__ kvtp,
                                                 const float* __restrict__ W2p,
                                                 const float* __restrict__ Sq,
                                                 const float* __restrict__ Ann,
                                                 const float* __restrict__ R,
                                                 float* __restrict__ out)
{
    __shared__ float yp[4][16];
    __shared__ float c2s[128];
    int bp = blockIdx.x >> 6, Xg = blockIdx.x & 63;
    int tid = threadIdx.x;

    if (tid < 128) {
        int n = tid;
        float r = 0.f;
        if (n < 100) {
            float S[11];
            #pragma unroll
            for (int J = 0; J < 11; ++J) {
                float s = 0.f;
                #pragma unroll
                for (int qq = 0; qq < 4; ++qq)
                    s += Sq[(size_t)(qq * 44 + bp * 11 + J) * 100 + n];
                S[J] = s;
            }
            float a = Ann[n];
            float seq[10];
            float v = a;
            seq[0] = v;
            #pragma unroll
            for (int s2 = 1; s2 < 10; ++s2) { v = clip1(v * a); seq[s2] = v; }
            r = S[10];
            #pragma unroll
            for (int J = 0; J < 10; ++J)
                r += seq[9 - J] * S[J];
        }
        c2s[n] = r;
    }
    __syncthreads();

    int wave = tid >> 6, lane = tid & 63;
    int X = Xg * 4 + wave;
    size_t base = (size_t)(bp * 12 + 11) * 65536 + (size_t)X * 256;
    const float* ao = Aoo + (size_t)X * 256;
    float red = 0.f;
    #pragma unroll
    for (int qq = 0; qq < 4; ++qq) {
        int xx = qq * 64 + lane;
        float kvv = 0.f;
        #pragma unroll
        for (int c = 0; c < KS; ++c)
            kvv += __half2float(kvtp[(size_t)c * KVT_STRIDE + base + xx]);
        red += wv[xx] * ao[xx] * kvv;
    }
    float w2a = 0.f, w2b = 0.f;
    #pragma unroll
    for (int g = 0; g < 4; ++g) {
        w2a += W2p[((size_t)g * 256 + X) * 100 + lane];
        if (lane < 36) w2b += W2p[((size_t)g * 256 + X) * 100 + 64 + lane];
    }
    red += c2s[lane] * w2a;
    if (lane < 36)
        red += c2s[64 + lane] * w2b;
    #pragma unroll
    for (int off = 32; off; off >>= 1) red += __shfl_xor(red, off);
    // all lanes hold hw[bp][X]
    if (lane < 16) yp[wave][lane] = red * R[((size_t)bp * 256 + X) * 16 + lane];
    __syncthreads();
    if (tid < 16) {
        float s = yp[0][tid] + yp[1][tid] + yp[2][tid] + yp[3][tid];
        atomicAdd(&out[bp * 16 + tid], s);
    }
}

// ---------------------------------------------------------------------------
extern "C" void kernel_launch(void* const* d_in, const int* in_sizes, int n_in,
                              void* d_out, int out_size, void* d_ws, size_t ws_size,
                              hipStream_t stream)
{
    const float* x   = (const float*)d_in[0];
    const float* K   = (const float*)d_in[1];
    const float* Q   = (const float*)d_in[2];
    const float* V   = (const float*)d_in[3];
    const float* Aoo = (const float*)d_in[4];
    const float* Ann = (const float*)d_in[5];
    const float* Aon = (const float*)d_in[6];
    const float* Ano = (const float*)d_in[7];
    const float* wv  = (const float*)d_in[8];
    float* out = (float*)d_out;

    char* ws = (char*)d_ws;
    const size_t o_Qh   = 0;                                  // 2 MB
    const size_t o_Kh   = o_Qh + (size_t)2 * 1024 * 1024;     // 2 MB
    const size_t o_ut   = o_Kh + (size_t)2 * 1024 * 1024;     // 384 KB (pad .5 MB)
    const size_t o_kvtp = o_ut + (size_t)512 * 1024;          // KS*6 MB (fp16)
    const size_t o_Sp   = o_kvtp + (size_t)KS * KVT_STRIDE * 2;
    const size_t o_Sq   = o_Sp + (size_t)512 * 4400 * 4;
    const size_t o_W2   = o_Sq + (size_t)17600 * 4 + 64;      // 4*256*100 f32
    const size_t o_R    = o_W2 + (size_t)102400 * 4;          // 4*256*16 f32

    __half* Qh  = (__half*)(ws + o_Qh);
    __half* Kh  = (__half*)(ws + o_Kh);
    __half* u_t = (__half*)(ws + o_ut);
    __half* kvtp = (__half*)(ws + o_kvtp);
    float* Sp   = (float*)(ws + o_Sp);
    float* Sq   = (float*)(ws + o_Sq);
    float* W2p  = (float*)(ws + o_W2);
    float* R    = (float*)(ws + o_R);

    hipLaunchKernelGGL(prep_kernel, dim3(2864), dim3(256), 0, stream,
                       K, Q, x, Aon, wv, V, Kh, Qh, u_t, W2p, R);
    hipLaunchKernelGGL(gemm_kvt,    dim3(768),  dim3(256), 0, stream, Kh, Qh, u_t, kvtp);
    hipLaunchKernelGGL(s_partial,   dim3(512),  dim3(256), 0, stream, Ano, kvtp, Sp);
    hipLaunchKernelGGL(reduce_s,    dim3(176),  dim3(128), 0, stream, Sp, Sq, out);
    hipLaunchKernelGGL(hw_kernel,   dim3(256),  dim3(256), 0, stream,
                       Aoo, wv, kvtp, W2p, Sq, Ann, R, out);
}

// Round 13
// 98.885 us; speedup vs baseline: 1.6905x; 1.0535x over previous
//
#include <hip/hip_runtime.h>
#include <hip/hip_fp16.h>

// ---------------------------------------------------------------------------
// NL=16, NS=256, NE=100, B=2, P=2, T=12
// x:(2,2,12,16,256) K/Q/V:(256,256,16) Aoo:(256,256) Ann:(100,)
// Aon/Ano:(256,256,100) w:(256,)  out:(2,2,1,16)=64 fp32
// kvt[bt][X][Y] = sum_j Kh[X,j]*u[bt,j]*Qh[Y,j],  j = x*16+c  (K=4096)
// ---------------------------------------------------------------------------

using f32x4 = __attribute__((ext_vector_type(4))) float;
using half8 = __attribute__((ext_vector_type(8))) _Float16;
using half4 = __attribute__((ext_vector_type(4))) _Float16;

#define KVT_STRIDE 3145728ull    // 48*65536 halves per K-chunk partial
#define KS 4

__device__ inline float clip1(float v) { return fminf(fmaxf(v, -1.f), 1.f); }

__device__ inline half8 mul8(uint4 a, uint4 b) {
    half8 x = __builtin_bit_cast(half8, a);
    half8 y = __builtin_bit_cast(half8, b);
    return x * y;                          // v_pk_mul_f16 x4
}

__device__ __forceinline__ void gl_lds16(const void* g, void* l) {
    __builtin_amdgcn_global_load_lds(
        (const __attribute__((address_space(1))) void*)g,
        (__attribute__((address_space(3))) void*)l, 16, 0, 0);
}

// ---------------------------------------------------------------------------
// prep: [0,512) K/Q -> fp16 (16 elem/thread) ; [512,560) u_t transpose.
// grid 560 x 256
// ---------------------------------------------------------------------------
__global__ void prep_kernel(const float* __restrict__ K, const float* __restrict__ Q,
                            const float* __restrict__ xin,
                            __half* __restrict__ Kh, __half* __restrict__ Qh,
                            __half* __restrict__ u_t)
{
    int b = blockIdx.x, t = threadIdx.x;
    if (b < 512) {
        bool isK = (b < 256);
        int bb = isK ? b : b - 256;
        size_t base = (size_t)bb * 4096 + t * 16;
        const f32x4* src = (const f32x4*)((isK ? K : Q) + base);
        __half* dst = (isK ? Kh : Qh) + base;
        #pragma unroll
        for (int j = 0; j < 2; ++j) {
            f32x4 v0 = src[j * 2], v1 = src[j * 2 + 1];
            half8 h;
            h[0] = (_Float16)v0.x; h[1] = (_Float16)v0.y;
            h[2] = (_Float16)v0.z; h[3] = (_Float16)v0.w;
            h[4] = (_Float16)v1.x; h[5] = (_Float16)v1.y;
            h[6] = (_Float16)v1.z; h[7] = (_Float16)v1.w;
            *(half8*)(dst + j * 8) = h;
        }
    } else {
        int bt = b - 512;                     // 0..47
        const float* src = xin + (size_t)bt * 4096;
        int xx = t;                           // 0..255
        half8 lo, hi;
        #pragma unroll
        for (int c = 0; c < 8; ++c)  lo[c] = (_Float16)src[c * 256 + xx];
        #pragma unroll
        for (int c = 0; c < 8; ++c)  hi[c] = (_Float16)src[(c + 8) * 256 + xx];
        half8* dst = (half8*)(u_t + (size_t)bt * 4096 + xx * 16);
        dst[0] = lo; dst[1] = hi;
    }
}

// ---------------------------------------------------------------------------
// GEMM: unchanged round-12 structure (passing): 128x128 tile, Kc=1024 (KS=4),
// BK=32, A reg-staged + u-scaled once + swizzled ds_write; B gl_lds DMA with
// pre-swizzled source; counted-vmcnt 2-ahead; 3 blk/CU; fp16 partials.
// ---------------------------------------------------------------------------
__global__ __launch_bounds__(256, 4) void gemm_kvt(
    const __half* __restrict__ Kh, const __half* __restrict__ Qh,
    const __half* __restrict__ u_t, __half* __restrict__ kvtp)
{
    __shared__ __half As[2][128][32];
    __shared__ __half Bs[2][128][32];
    __shared__ __half u_s[1024];

    int bid = blockIdx.x;
    int work = (bid & 7) * 96 + (bid >> 3);
    int kc = work / 192;
    int rem = work - kc * 192;
    int tile = rem / 48;
    int bt = rem - tile * 48;
    int Xb = (tile >> 1) * 128, Yb = (tile & 1) * 128;
    int kbase = kc * 1024;

    int tid = threadIdx.x;
    if (tid < 128)
        *(uint4*)&u_s[tid * 8] = *(const uint4*)(u_t + (size_t)bt * 4096 + kbase + tid * 8);
    __syncthreads();

    int wave = tid >> 6, lane = tid & 63;

    int arow = tid >> 1;
    int apair = (tid & 1) * 2;
    const __half* gA = Kh + (size_t)(Xb + arow) * 4096 + kbase + apair * 8;
    int aswz = (arow >> 1) & 3;
    int asb0 = ((apair + 0) ^ aswz) << 4;
    int asb1 = ((apair + 1) ^ aswz) << 4;

    int srow = lane >> 2;
    int sk = ((lane & 3) ^ ((srow >> 1) & 3)) << 3;
    const __half* gB = Qh + (size_t)(Yb + wave * 16 + srow) * 4096 + kbase + sk;

    int wr = (wave >> 1) * 64, wc = (wave & 1) * 64;
    int lrow = lane & 15, kg = lane >> 4;
    int fb = (kg * 16) ^ (((lrow >> 1) & 3) << 4);

    f32x4 acc[4][4];
    f32x4 zero = {0.f, 0.f, 0.f, 0.f};
    #pragma unroll
    for (int m = 0; m < 4; ++m)
        #pragma unroll
        for (int n = 0; n < 4; ++n) acc[m][n] = zero;

    #define ISSUE_B(s, buf)                                                    \
        do {                                                                   \
            _Pragma("unroll")                                                  \
            for (int i_ = 0; i_ < 2; ++i_)                                     \
                gl_lds16(gB + (size_t)(i_ * 64) * 4096 + (s) * 32,             \
                         &Bs[buf][i_ * 64 + wave * 16][0]);                    \
        } while (0)

    #define WRITE_A(s, r0, r1, buf)                                            \
        do {                                                                   \
            uint4 uv0 = *(const uint4*)&u_s[(s) * 32 + apair * 8];             \
            uint4 uv1 = *(const uint4*)&u_s[(s) * 32 + apair * 8 + 8];         \
            *(half8*)((char*)&As[buf][arow][0] + asb0) = mul8(r0, uv0);        \
            *(half8*)((char*)&As[buf][arow][0] + asb1) = mul8(r1, uv1);        \
        } while (0)

    #define COMPUTE(cur)                                                       \
        do {                                                                   \
            half8 af[4], bf[4];                                                \
            _Pragma("unroll")                                                  \
            for (int m = 0; m < 4; ++m)                                        \
                af[m] = *(const half8*)((const char*)&As[cur][wr + m * 16 + lrow][0] + fb); \
            _Pragma("unroll")                                                  \
            for (int n = 0; n < 4; ++n)                                        \
                bf[n] = *(const half8*)((const char*)&Bs[cur][wc + n * 16 + lrow][0] + fb); \
            _Pragma("unroll")                                                  \
            for (int m = 0; m < 4; ++m)                                        \
                _Pragma("unroll")                                              \
                for (int n = 0; n < 4; ++n)                                    \
                    acc[m][n] = __builtin_amdgcn_mfma_f32_16x16x32_f16(af[m], bf[n], acc[m][n], 0, 0, 0); \
        } while (0)

    #define STEP(s, c0, c1, i0, i1, cur)                                       \
        do {                                                                   \
            if ((s) < 31) asm volatile("s_waitcnt vmcnt(4) lgkmcnt(0)" ::: "memory"); \
            else          asm volatile("s_waitcnt vmcnt(0) lgkmcnt(0)" ::: "memory"); \
            __builtin_amdgcn_s_barrier();                                      \
            __builtin_amdgcn_sched_barrier(0);                                 \
            COMPUTE(cur);                                                      \
            asm volatile("s_waitcnt lgkmcnt(0)" ::: "memory");                 \
            __builtin_amdgcn_s_barrier();                                      \
            __builtin_amdgcn_sched_barrier(0);                                 \
            if ((s) + 2 < 32) {                                                \
                const __half* a_ = gA + ((s) + 2) * 32;                        \
                i0 = *(const uint4*)a_;                                        \
                i1 = *(const uint4*)(a_ + 8);                                  \
                ISSUE_B((s) + 2, cur);                                         \
            }                                                                  \
            if ((s) + 1 < 32) WRITE_A((s) + 1, c0, c1, (cur) ^ 1);             \
        } while (0)

    uint4 aP0, aP1, aC0, aC1;
    aP0 = *(const uint4*)gA;
    aP1 = *(const uint4*)(gA + 8);
    ISSUE_B(0, 0);
    aC0 = *(const uint4*)(gA + 32);
    aC1 = *(const uint4*)(gA + 40);
    ISSUE_B(1, 1);
    WRITE_A(0, aP0, aP1, 0);

    #pragma unroll
    for (int s = 0; s < 32; s += 2) {
        STEP(s,     aC0, aC1, aP0, aP1, 0);
        STEP(s + 1, aP0, aP1, aC0, aC1, 1);
    }
    #undef STEP
    #undef COMPUTE
    #undef WRITE_A
    #undef ISSUE_B

    __half* outp = kvtp + (size_t)kc * KVT_STRIDE + (size_t)bt * 65536;
    int row0 = Xb + wr + kg * 4;
    int col0 = Yb + wc + lrow;
    #pragma unroll
    for (int m = 0; m < 4; ++m)
        #pragma unroll
        for (int n = 0; n < 4; ++n)
            #pragma unroll
            for (int rr = 0; rr < 4; ++rr)
                outp[(size_t)(row0 + m * 16 + rr) * 256 + col0 + n * 16] =
                    __float2half(acc[m][n][rr]);
}

// ---------------------------------------------------------------------------
// mid: [0,512) s_partial (transposed-Ano) ; [512,768) R ; [768,1280) W2p.
// One shared buffer aliased per branch (75.3 KB -> 2 blocks/CU).
// ---------------------------------------------------------------------------
__global__ __launch_bounds__(256) void mid_kernel(
    const float* __restrict__ Ano, const __half* __restrict__ kvtp,
    const float* __restrict__ V, const float* __restrict__ xin,
    const float* __restrict__ Aon, const float* __restrict__ wv,
    float* __restrict__ Sp, float* __restrict__ R, float* __restrict__ W2p)
{
    __shared__ __align__(16) char smem[75328];
    int b = blockIdx.x, tid = threadIdx.x;

    if (b < 512) {
        // ---- s_partial: Sp[cb][bp][J][n] = sum_k clip(Ano[k][n])*kvt[bp*12+J][k]
        float* anoT = (float*)smem;                         // [100][132]
        float (*kvt_s)[128] = (float(*)[128])(smem + 52800); // [44][128]
        int cb = b;
        int k0 = cb * 128;

        {   // stage Ano chunk transposed+clipped: anoT[n][k], stride 132
            const f32x4* src = (const f32x4*)(Ano + (size_t)k0 * 100);
            for (int i = tid; i < 3200; i += 256) {
                f32x4 f = __builtin_nontemporal_load(src + i);
                int e = i * 4;
                int k = e / 100;
                int n = e - k * 100;
                #pragma unroll
                for (int j = 0; j < 4; ++j) {
                    int nn = n + j, kk2 = k;
                    if (nn >= 100) { nn -= 100; ++kk2; }
                    anoT[nn * 132 + kk2] = clip1(f[j]);
                }
            }
        }
        {   // stage kvt rows (sum of KS fp16 partials)
            for (int idx = tid; idx < 5632; idx += 256) {
                int rI = idx >> 7, k = idx & 127;
                int bpr = rI / 11, Jr = rI - bpr * 11;
                size_t off = (size_t)(bpr * 12 + Jr) * 65536 + k0 + k;
                float v = 0.f;
                #pragma unroll
                for (int c = 0; c < KS; ++c)
                    v += __half2float(kvtp[(size_t)c * KVT_STRIDE + off]);
                kvt_s[rI][k] = v;
            }
        }
        __syncthreads();

        int lane = tid & 63;
        int bp = tid >> 6;
        bool has2 = lane < 36;
        float acc0[11], acc1[11];
        #pragma unroll
        for (int J = 0; J < 11; ++J) { acc0[J] = 0.f; acc1[J] = 0.f; }

        const float* a0p = anoT + lane * 132;
        const float* a1p = anoT + (64 + lane) * 132;
        for (int k = 0; k < 128; k += 4) {
            f32x4 kv[11];
            #pragma unroll
            for (int J = 0; J < 11; ++J)
                kv[J] = *(const f32x4*)&kvt_s[bp * 11 + J][k];
            f32x4 a0v = *(const f32x4*)(a0p + k);
            f32x4 a1v = {0.f, 0.f, 0.f, 0.f};
            if (has2) a1v = *(const f32x4*)(a1p + k);
            #pragma unroll
            for (int kk = 0; kk < 4; ++kk) {
                #pragma unroll
                for (int J = 0; J < 11; ++J) {
                    acc0[J] += kv[J][kk] * a0v[kk];
                    acc1[J] += kv[J][kk] * a1v[kk];
                }
            }
        }
        float* outb = Sp + ((size_t)cb * 4 + bp) * 1100;
        #pragma unroll
        for (int J = 0; J < 11; ++J) {
            outb[J * 100 + lane] = acc0[J];
            if (has2) outb[J * 100 + 64 + lane] = acc1[J];
        }
    } else if (b < 768) {
        // ---- R[bp][X][c] = sum_x xlast[bp][c][x] * V[X][x*16+c]
        float* vrow = (float*)smem;                         // [4096]
        int X = b - 512;
        {
            const float4* src = (const float4*)(V + (size_t)X * 4096);
            float4* dst = (float4*)vrow;
            for (int i = tid; i < 1024; i += 256) dst[i] = src[i];
        }
        __syncthreads();
        int bp = tid >> 6, c = (tid >> 2) & 15, g = tid & 3;
        const float* xl = xin + ((size_t)(bp * 12) + 11) * 4096 + c * 256;
        float p = 0.f;
        #pragma unroll 4
        for (int x = g * 64; x < g * 64 + 64; ++x)
            p += xl[x] * vrow[x * 16 + c];
        p += __shfl_xor(p, 1);
        p += __shfl_xor(p, 2);
        if (g == 0) R[((size_t)bp * 256 + X) * 16 + c] = p;
    } else {
        // ---- W2p[g][X][n] = sum_{bb in g*64..+64} w[bb]*clip(Aon[X,bb,n])
        int idx = b - 768;                    // 0..511
        int X = idx >> 1, h = idx & 1;
        int g = h * 2 + (tid >> 7), n = tid & 127;
        if (n < 100) {
            const float* base = Aon + (size_t)X * 25600 + (size_t)g * 6400 + n;
            float acc = 0.f;
            for (int bb = 0; bb < 64; ++bb)
                acc += wv[g * 64 + bb] * clip1(__builtin_nontemporal_load(base + (size_t)bb * 100));
            W2p[((size_t)g * 256 + X) * 100 + n] = acc;
        }
    }
}

// Sq[qq][bp*11+J][n] = sum_{cb in quarter qq} Sp[cb][bp][J][n] ; grid 176 x 128
// block 0 also zeroes out[64] (hw accumulates into it afterwards)
__global__ void reduce_s(const float* __restrict__ Sp, float* __restrict__ Sq,
                         float* __restrict__ out)
{
    int bid = blockIdx.x;
    int t = threadIdx.x;
    if (bid == 0 && t < 64) out[t] = 0.f;
    int qq = bid & 3, idx = bid >> 2;       // idx 0..43
    int bp = idx / 11, J = idx - bp * 11;
    if (t >= 100) return;
    float acc = 0.f;
    for (int c = qq * 128; c < qq * 128 + 128; ++c)
        acc += Sp[((size_t)c * 4 + bp) * 1100 + J * 100 + t];
    Sq[(size_t)(qq * 44 + idx) * 100 + t] = acc;
}

// hw[bp][X] = sum_x w[x]*Aoo[X,x]*kvt11[X,x] + sum_n c2[bp][n]*W2[X][n]
// c2 recomputed per block from Sq (LDS); y via atomicAdd(out).
// grid 256 (bp*64+Xg) x 256
__global__ __launch_bounds__(256) void hw_kernel(const float* __restrict__ Aoo,
                                                 const float* __restrict__ wv,
                                                 const __half* __restrict__ kvtp,
                                                 const float* __restrict__ W2p,
                                                 const float* __restrict__ Sq,
                                                 const float* __restrict__ Ann,
                                                 const float* __restrict__ R,
                                                 float* __restrict__ out)
{
    __shared__ float yp[4][16];
    __shared__ float c2s[128];
    int bp = blockIdx.x >> 6, Xg = blockIdx.x & 63;
    int tid = threadIdx.x;

    if (tid < 128) {
        int n = tid;
        float r = 0.f;
        if (n < 100) {
            float S[11];
            #pragma unroll
            for (int J = 0; J < 11; ++J) {
                float s = 0.f;
                #pragma unroll
                for (int qq = 0; qq < 4; ++qq)
                    s += Sq[(size_t)(qq * 44 + bp * 11 + J) * 100 + n];
                S[J] = s;
            }
            float a = Ann[n];
            float seq[10];
            float v = a;
            seq[0] = v;
            #pragma unroll
            for (int s2 = 1; s2 < 10; ++s2) { v = clip1(v * a); seq[s2] = v; }
            r = S[10];
            #pragma unroll
            for (int J = 0; J < 10; ++J)
                r += seq[9 - J] * S[J];
        }
        c2s[n] = r;
    }
    __syncthreads();

    int wave = tid >> 6, lane = tid & 63;
    int X = Xg * 4 + wave;
    size_t base = (size_t)(bp * 12 + 11) * 65536 + (size_t)X * 256;
    const float* ao = Aoo + (size_t)X * 256;
    float red = 0.f;
    #pragma unroll
    for (int qq = 0; qq < 4; ++qq) {
        int xx = qq * 64 + lane;
        float kvv = 0.f;
        #pragma unroll
        for (int c = 0; c < KS; ++c)
            kvv += __half2float(kvtp[(size_t)c * KVT_STRIDE + base + xx]);
        red += wv[xx] * ao[xx] * kvv;
    }
    float w2a = 0.f, w2b = 0.f;
    #pragma unroll
    for (int g = 0; g < 4; ++g) {
        w2a += W2p[((size_t)g * 256 + X) * 100 + lane];
        if (lane < 36) w2b += W2p[((size_t)g * 256 + X) * 100 + 64 + lane];
    }
    red += c2s[lane] * w2a;
    if (lane < 36)
        red += c2s[64 + lane] * w2b;
    #pragma unroll
    for (int off = 32; off; off >>= 1) red += __shfl_xor(red, off);
    if (lane < 16) yp[wave][lane] = red * R[((size_t)bp * 256 + X) * 16 + lane];
    __syncthreads();
    if (tid < 16) {
        float s = yp[0][tid] + yp[1][tid] + yp[2][tid] + yp[3][tid];
        atomicAdd(&out[bp * 16 + tid], s);
    }
}

// ---------------------------------------------------------------------------
extern "C" void kernel_launch(void* const* d_in, const int* in_sizes, int n_in,
                              void* d_out, int out_size, void* d_ws, size_t ws_size,
                              hipStream_t stream)
{
    const float* x   = (const float*)d_in[0];
    const float* K   = (const float*)d_in[1];
    const float* Q   = (const float*)d_in[2];
    const float* V   = (const float*)d_in[3];
    const float* Aoo = (const float*)d_in[4];
    const float* Ann = (const float*)d_in[5];
    const float* Aon = (const float*)d_in[6];
    const float* Ano = (const float*)d_in[7];
    const float* wv  = (const float*)d_in[8];
    float* out = (float*)d_out;

    char* ws = (char*)d_ws;
    const size_t o_Qh   = 0;                                  // 2 MB
    const size_t o_Kh   = o_Qh + (size_t)2 * 1024 * 1024;     // 2 MB
    const size_t o_ut   = o_Kh + (size_t)2 * 1024 * 1024;     // 384 KB (pad .5 MB)
    const size_t o_kvtp = o_ut + (size_t)512 * 1024;          // KS*6 MB (fp16)
    const size_t o_Sp   = o_kvtp + (size_t)KS * KVT_STRIDE * 2;
    const size_t o_Sq   = o_Sp + (size_t)512 * 4400 * 4;
    const size_t o_W2   = o_Sq + (size_t)17600 * 4 + 64;      // 4*256*100 f32
    const size_t o_R    = o_W2 + (size_t)102400 * 4;          // 4*256*16 f32

    __half* Qh  = (__half*)(ws + o_Qh);
    __half* Kh  = (__half*)(ws + o_Kh);
    __half* u_t = (__half*)(ws + o_ut);
    __half* kvtp = (__half*)(ws + o_kvtp);
    float* Sp   = (float*)(ws + o_Sp);
    float* Sq   = (float*)(ws + o_Sq);
    float* W2p  = (float*)(ws + o_W2);
    float* R    = (float*)(ws + o_R);

    hipLaunchKernelGGL(prep_kernel, dim3(560),  dim3(256), 0, stream,
                       K, Q, x, Kh, Qh, u_t);
    hipLaunchKernelGGL(gemm_kvt,    dim3(768),  dim3(256), 0, stream, Kh, Qh, u_t, kvtp);
    hipLaunchKernelGGL(mid_kernel,  dim3(1280), dim3(256), 0, stream,
                       Ano, kvtp, V, x, Aon, wv, Sp, R, W2p);
    hipLaunchKernelGGL(reduce_s,    dim3(176),  dim3(128), 0, stream, Sp, Sq, out);
    hipLaunchKernelGGL(hw_kernel,   dim3(256),  dim3(256), 0, stream,
                       Aoo, wv, kvtp, W2p, Sq, Ann, R, out);
}

// Round 14
// 87.842 us; speedup vs baseline: 1.9030x; 1.1257x over previous
//
#include <hip/hip_runtime.h>
#include <hip/hip_fp16.h>

// ---------------------------------------------------------------------------
// NL=16, NS=256, NE=100, B=2, P=2, T=12
// x:(2,2,12,16,256) K/Q/V:(256,256,16) Aoo:(256,256) Ann:(100,)
// Aon/Ano:(256,256,100) w:(256,)  out:(2,2,1,16)=64 fp32
// kvt[bt][X][Y] = sum_j Kh[X,j]*u[bt,j]*Qh[Y,j],  j = x*16+c  (K=4096)
// ---------------------------------------------------------------------------

using f32x4 = __attribute__((ext_vector_type(4))) float;
using half8 = __attribute__((ext_vector_type(8))) _Float16;
using half4 = __attribute__((ext_vector_type(4))) _Float16;

#define KVT_STRIDE 3145728ull    // 48*65536 halves per K-chunk partial
#define KS 4

__device__ inline float clip1(float v) { return fminf(fmaxf(v, -1.f), 1.f); }

__device__ inline half8 mul8(uint4 a, uint4 b) {
    half8 x = __builtin_bit_cast(half8, a);
    half8 y = __builtin_bit_cast(half8, b);
    return x * y;                          // v_pk_mul_f16 x4
}

__device__ __forceinline__ void gl_lds16(const void* g, void* l) {
    __builtin_amdgcn_global_load_lds(
        (const __attribute__((address_space(1))) void*)g,
        (__attribute__((address_space(3))) void*)l, 16, 0, 0);
}

// ---------------------------------------------------------------------------
// prep: [0,512) K/Q -> fp16 (16 elem/thread) ; [512,560) u_t transpose.
// grid 560 x 256
// ---------------------------------------------------------------------------
__global__ void prep_kernel(const float* __restrict__ K, const float* __restrict__ Q,
                            const float* __restrict__ xin,
                            __half* __restrict__ Kh, __half* __restrict__ Qh,
                            __half* __restrict__ u_t)
{
    int b = blockIdx.x, t = threadIdx.x;
    if (b < 512) {
        bool isK = (b < 256);
        int bb = isK ? b : b - 256;
        size_t base = (size_t)bb * 4096 + t * 16;
        const f32x4* src = (const f32x4*)((isK ? K : Q) + base);
        __half* dst = (isK ? Kh : Qh) + base;
        #pragma unroll
        for (int j = 0; j < 2; ++j) {
            f32x4 v0 = src[j * 2], v1 = src[j * 2 + 1];
            half8 h;
            h[0] = (_Float16)v0.x; h[1] = (_Float16)v0.y;
            h[2] = (_Float16)v0.z; h[3] = (_Float16)v0.w;
            h[4] = (_Float16)v1.x; h[5] = (_Float16)v1.y;
            h[6] = (_Float16)v1.z; h[7] = (_Float16)v1.w;
            *(half8*)(dst + j * 8) = h;
        }
    } else {
        int bt = b - 512;                     // 0..47
        const float* src = xin + (size_t)bt * 4096;
        int xx = t;                           // 0..255
        half8 lo, hi;
        #pragma unroll
        for (int c = 0; c < 8; ++c)  lo[c] = (_Float16)src[c * 256 + xx];
        #pragma unroll
        for (int c = 0; c < 8; ++c)  hi[c] = (_Float16)src[(c + 8) * 256 + xx];
        half8* dst = (half8*)(u_t + (size_t)bt * 4096 + xx * 16);
        dst[0] = lo; dst[1] = hi;
    }
}

// ---------------------------------------------------------------------------
// GEMM: unchanged round-12 structure (passing): 128x128 tile, Kc=1024 (KS=4),
// BK=32, A reg-staged + u-scaled once + swizzled ds_write; B gl_lds DMA with
// pre-swizzled source; counted-vmcnt 2-ahead; fp16 partials.
// ---------------------------------------------------------------------------
__global__ __launch_bounds__(256, 4) void gemm_kvt(
    const __half* __restrict__ Kh, const __half* __restrict__ Qh,
    const __half* __restrict__ u_t, __half* __restrict__ kvtp)
{
    __shared__ __half As[2][128][32];
    __shared__ __half Bs[2][128][32];
    __shared__ __half u_s[1024];

    int bid = blockIdx.x;
    int work = (bid & 7) * 96 + (bid >> 3);
    int kc = work / 192;
    int rem = work - kc * 192;
    int tile = rem / 48;
    int bt = rem - tile * 48;
    int Xb = (tile >> 1) * 128, Yb = (tile & 1) * 128;
    int kbase = kc * 1024;

    int tid = threadIdx.x;
    if (tid < 128)
        *(uint4*)&u_s[tid * 8] = *(const uint4*)(u_t + (size_t)bt * 4096 + kbase + tid * 8);
    __syncthreads();

    int wave = tid >> 6, lane = tid & 63;

    int arow = tid >> 1;
    int apair = (tid & 1) * 2;
    const __half* gA = Kh + (size_t)(Xb + arow) * 4096 + kbase + apair * 8;
    int aswz = (arow >> 1) & 3;
    int asb0 = ((apair + 0) ^ aswz) << 4;
    int asb1 = ((apair + 1) ^ aswz) << 4;

    int srow = lane >> 2;
    int sk = ((lane & 3) ^ ((srow >> 1) & 3)) << 3;
    const __half* gB = Qh + (size_t)(Yb + wave * 16 + srow) * 4096 + kbase + sk;

    int wr = (wave >> 1) * 64, wc = (wave & 1) * 64;
    int lrow = lane & 15, kg = lane >> 4;
    int fb = (kg * 16) ^ (((lrow >> 1) & 3) << 4);

    f32x4 acc[4][4];
    f32x4 zero = {0.f, 0.f, 0.f, 0.f};
    #pragma unroll
    for (int m = 0; m < 4; ++m)
        #pragma unroll
        for (int n = 0; n < 4; ++n) acc[m][n] = zero;

    #define ISSUE_B(s, buf)                                                    \
        do {                                                                   \
            _Pragma("unroll")                                                  \
            for (int i_ = 0; i_ < 2; ++i_)                                     \
                gl_lds16(gB + (size_t)(i_ * 64) * 4096 + (s) * 32,             \
                         &Bs[buf][i_ * 64 + wave * 16][0]);                    \
        } while (0)

    #define WRITE_A(s, r0, r1, buf)                                            \
        do {                                                                   \
            uint4 uv0 = *(const uint4*)&u_s[(s) * 32 + apair * 8];             \
            uint4 uv1 = *(const uint4*)&u_s[(s) * 32 + apair * 8 + 8];         \
            *(half8*)((char*)&As[buf][arow][0] + asb0) = mul8(r0, uv0);        \
            *(half8*)((char*)&As[buf][arow][0] + asb1) = mul8(r1, uv1);        \
        } while (0)

    #define COMPUTE(cur)                                                       \
        do {                                                                   \
            half8 af[4], bf[4];                                                \
            _Pragma("unroll")                                                  \
            for (int m = 0; m < 4; ++m)                                        \
                af[m] = *(const half8*)((const char*)&As[cur][wr + m * 16 + lrow][0] + fb); \
            _Pragma("unroll")                                                  \
            for (int n = 0; n < 4; ++n)                                        \
                bf[n] = *(const half8*)((const char*)&Bs[cur][wc + n * 16 + lrow][0] + fb); \
            _Pragma("unroll")                                                  \
            for (int m = 0; m < 4; ++m)                                        \
                _Pragma("unroll")                                              \
                for (int n = 0; n < 4; ++n)                                    \
                    acc[m][n] = __builtin_amdgcn_mfma_f32_16x16x32_f16(af[m], bf[n], acc[m][n], 0, 0, 0); \
        } while (0)

    #define STEP(s, c0, c1, i0, i1, cur)                                       \
        do {                                                                   \
            if ((s) < 31) asm volatile("s_waitcnt vmcnt(4) lgkmcnt(0)" ::: "memory"); \
            else          asm volatile("s_waitcnt vmcnt(0) lgkmcnt(0)" ::: "memory"); \
            __builtin_amdgcn_s_barrier();                                      \
            __builtin_amdgcn_sched_barrier(0);                                 \
            COMPUTE(cur);                                                      \
            asm volatile("s_waitcnt lgkmcnt(0)" ::: "memory");                 \
            __builtin_amdgcn_s_barrier();                                      \
            __builtin_amdgcn_sched_barrier(0);                                 \
            if ((s) + 2 < 32) {                                                \
                const __half* a_ = gA + ((s) + 2) * 32;                        \
                i0 = *(const uint4*)a_;                                        \
                i1 = *(const uint4*)(a_ + 8);                                  \
                ISSUE_B((s) + 2, cur);                                         \
            }                                                                  \
            if ((s) + 1 < 32) WRITE_A((s) + 1, c0, c1, (cur) ^ 1);             \
        } while (0)

    uint4 aP0, aP1, aC0, aC1;
    aP0 = *(const uint4*)gA;
    aP1 = *(const uint4*)(gA + 8);
    ISSUE_B(0, 0);
    aC0 = *(const uint4*)(gA + 32);
    aC1 = *(const uint4*)(gA + 40);
    ISSUE_B(1, 1);
    WRITE_A(0, aP0, aP1, 0);

    #pragma unroll
    for (int s = 0; s < 32; s += 2) {
        STEP(s,     aC0, aC1, aP0, aP1, 0);
        STEP(s + 1, aP0, aP1, aC0, aC1, 1);
    }
    #undef STEP
    #undef COMPUTE
    #undef WRITE_A
    #undef ISSUE_B

    __half* outp = kvtp + (size_t)kc * KVT_STRIDE + (size_t)bt * 65536;
    int row0 = Xb + wr + kg * 4;
    int col0 = Yb + wc + lrow;
    #pragma unroll
    for (int m = 0; m < 4; ++m)
        #pragma unroll
        for (int n = 0; n < 4; ++n)
            #pragma unroll
            for (int rr = 0; rr < 4; ++rr)
                outp[(size_t)(row0 + m * 16 + rr) * 256 + col0 + n * 16] =
                    __float2half(acc[m][n][rr]);
}

// ---------------------------------------------------------------------------
// mid: [0,512) s_partial ; [512,768) R ; [768,1280) W2p.
// s_partial smem = anoH fp16 [128][100](+64 pad) 25.7KB + kvt_s[44][132] f32
// 23.2KB = 48.9KB -> 3 blocks/CU. Vectorized kvt staging (uint4 per partial).
// ---------------------------------------------------------------------------
__global__ __launch_bounds__(256) void mid_kernel(
    const float* __restrict__ Ano, const __half* __restrict__ kvtp,
    const float* __restrict__ V, const float* __restrict__ xin,
    const float* __restrict__ Aon, const float* __restrict__ wv,
    float* __restrict__ Sp, float* __restrict__ R, float* __restrict__ W2p)
{
    __shared__ __align__(16) char smem[48960];
    int b = blockIdx.x, tid = threadIdx.x;

    if (b < 512) {
        // ---- s_partial: Sp[cb][bp][J][n] = sum_k clip(Ano[k][n])*kvt[bp*12+J][k]
        __half* anoH = (__half*)smem;                        // [128*100 + 64]
        float (*kvt_s)[132] = (float(*)[132])(smem + 25728); // [44][132]
        int cb = b;
        int k0 = cb * 128;

        {   // stage Ano chunk clipped -> fp16, layout [k][n] contiguous
            const f32x4* src = (const f32x4*)(Ano + (size_t)k0 * 100);
            for (int i = tid; i < 3200; i += 256) {
                f32x4 f = __builtin_nontemporal_load(src + i);
                half4 h;
                h[0] = (_Float16)clip1(f.x); h[1] = (_Float16)clip1(f.y);
                h[2] = (_Float16)clip1(f.z); h[3] = (_Float16)clip1(f.w);
                *(half4*)&anoH[i * 4] = h;
            }
        }
        {   // stage kvt rows: vectorized — 44 rows x 16 groups of 8 halves
            for (int idx = tid; idx < 704; idx += 256) {
                int rI = idx >> 4, g = idx & 15;
                int bpr = rI / 11, Jr = rI - bpr * 11;
                const __half* p = kvtp + (size_t)(bpr * 12 + Jr) * 65536 + k0 + g * 8;
                half8 v0 = *(const half8*)(p);
                half8 v1 = *(const half8*)(p + KVT_STRIDE);
                half8 v2 = *(const half8*)(p + 2 * KVT_STRIDE);
                half8 v3 = *(const half8*)(p + 3 * KVT_STRIDE);
                f32x4 lo, hi;
                #pragma unroll
                for (int j = 0; j < 4; ++j) {
                    lo[j] = (float)v0[j] + (float)v1[j] + (float)v2[j] + (float)v3[j];
                    hi[j] = (float)v0[j+4] + (float)v1[j+4] + (float)v2[j+4] + (float)v3[j+4];
                }
                *(f32x4*)&kvt_s[rI][g * 8]     = lo;
                *(f32x4*)&kvt_s[rI][g * 8 + 4] = hi;
            }
        }
        __syncthreads();

        int lane = tid & 63;
        int bp = tid >> 6;
        bool has2 = lane < 36;
        float acc0[11], acc1[11];
        #pragma unroll
        for (int J = 0; J < 11; ++J) { acc0[J] = 0.f; acc1[J] = 0.f; }

        for (int k = 0; k < 128; k += 4) {
            f32x4 kv[11];
            #pragma unroll
            for (int J = 0; J < 11; ++J)
                kv[J] = *(const f32x4*)&kvt_s[bp * 11 + J][k];
            #pragma unroll
            for (int kk = 0; kk < 4; ++kk) {
                float a0 = (float)anoH[(k + kk) * 100 + lane];
                float a1r = (float)anoH[(k + kk) * 100 + 64 + lane];
                float a1 = has2 ? a1r : 0.f;
                #pragma unroll
                for (int J = 0; J < 11; ++J) {
                    acc0[J] += kv[J][kk] * a0;
                    acc1[J] += kv[J][kk] * a1;
                }
            }
        }
        float* outb = Sp + ((size_t)cb * 4 + bp) * 1100;
        #pragma unroll
        for (int J = 0; J < 11; ++J) {
            outb[J * 100 + lane] = acc0[J];
            if (has2) outb[J * 100 + 64 + lane] = acc1[J];
        }
    } else if (b < 768) {
        // ---- R[bp][X][c] = sum_x xlast[bp][c][x] * V[X][x*16+c]
        float* vrow = (float*)smem;                         // [4096]
        int X = b - 512;
        {
            const float4* src = (const float4*)(V + (size_t)X * 4096);
            float4* dst = (float4*)vrow;
            for (int i = tid; i < 1024; i += 256) dst[i] = src[i];
        }
        __syncthreads();
        int bp = tid >> 6, c = (tid >> 2) & 15, g = tid & 3;
        const float* xl = xin + ((size_t)(bp * 12) + 11) * 4096 + c * 256;
        float p = 0.f;
        #pragma unroll 4
        for (int x = g * 64; x < g * 64 + 64; ++x)
            p += xl[x] * vrow[x * 16 + c];
        p += __shfl_xor(p, 1);
        p += __shfl_xor(p, 2);
        if (g == 0) R[((size_t)bp * 256 + X) * 16 + c] = p;
    } else {
        // ---- W2p[g][X][n] = sum_{bb in g*64..+64} w[bb]*clip(Aon[X,bb,n])
        int idx = b - 768;                    // 0..511
        int X = idx >> 1, h = idx & 1;
        int g = h * 2 + (tid >> 7), n = tid & 127;
        if (n < 100) {
            const float* base = Aon + (size_t)X * 25600 + (size_t)g * 6400 + n;
            float acc = 0.f;
            for (int bb = 0; bb < 64; ++bb)
                acc += wv[g * 64 + bb] * clip1(__builtin_nontemporal_load(base + (size_t)bb * 100));
            W2p[((size_t)g * 256 + X) * 100 + n] = acc;
        }
    }
}

// Sq[qq][bp*11+J][n] = sum_{cb in eighth qq} Sp[cb][bp][J][n] ; grid 352 x 128
// block 0 also zeroes out[64] (hw accumulates into it afterwards)
__global__ void reduce_s(const float* __restrict__ Sp, float* __restrict__ Sq,
                         float* __restrict__ out)
{
    int bid = blockIdx.x;
    int t = threadIdx.x;
    if (bid == 0 && t < 64) out[t] = 0.f;
    int qq = bid & 7, idx = bid >> 3;       // idx 0..43
    int bp = idx / 11, J = idx - bp * 11;
    if (t >= 100) return;
    float acc = 0.f;
    for (int c = qq * 64; c < qq * 64 + 64; ++c)
        acc += Sp[((size_t)c * 4 + bp) * 1100 + J * 100 + t];
    Sq[(size_t)(qq * 44 + idx) * 100 + t] = acc;
}

// hw[bp][X] = sum_x w[x]*Aoo[X,x]*kvt11[X,x] + sum_n c2[bp][n]*W2[X][n]
// c2 recomputed per block from Sq (LDS, 8 quarters); y via atomicAdd(out).
// grid 256 (bp*64+Xg) x 256
__global__ __launch_bounds__(256) void hw_kernel(const float* __restrict__ Aoo,
                                                 const float* __restrict__ wv,
                                                 const __half* __restrict__ kvtp,
                                                 const float* __restrict__ W2p,
                                                 const float* __restrict__ Sq,
                                                 const float* __restrict__ Ann,
                                                 const float* __restrict__ R,
                                                 float* __restrict__ out)
{
    __shared__ float yp[4][16];
    __shared__ float c2s[128];
    int bp = blockIdx.x >> 6, Xg = blockIdx.x & 63;
    int tid = threadIdx.x;

    if (tid < 128) {
        int n = tid;
        float r = 0.f;
        if (n < 100) {
            float S[11];
            #pragma unroll
            for (int J = 0; J < 11; ++J) {
                float s = 0.f;
                #pragma unroll
                for (int qq = 0; qq < 8; ++qq)
                    s += Sq[(size_t)(qq * 44 + bp * 11 + J) * 100 + n];
                S[J] = s;
            }
            float a = Ann[n];
            float seq[10];
            float v = a;
            seq[0] = v;
            #pragma unroll
            for (int s2 = 1; s2 < 10; ++s2) { v = clip1(v * a); seq[s2] = v; }
            r = S[10];
            #pragma unroll
            for (int J = 0; J < 10; ++J)
                r += seq[9 - J] * S[J];
        }
        c2s[n] = r;
    }
    __syncthreads();

    int wave = tid >> 6, lane = tid & 63;
    int X = Xg * 4 + wave;
    size_t base = (size_t)(bp * 12 + 11) * 65536 + (size_t)X * 256;
    const float* ao = Aoo + (size_t)X * 256;
    float red = 0.f;
    #pragma unroll
    for (int qq = 0; qq < 4; ++qq) {
        int xx = qq * 64 + lane;
        float kvv = 0.f;
        #pragma unroll
        for (int c = 0; c < KS; ++c)
            kvv += __half2float(kvtp[(size_t)c * KVT_STRIDE + base + xx]);
        red += wv[xx] * ao[xx] * kvv;
    }
    float w2a = 0.f, w2b = 0.f;
    #pragma unroll
    for (int g = 0; g < 4; ++g) {
        w2a += W2p[((size_t)g * 256 + X) * 100 + lane];
        if (lane < 36) w2b += W2p[((size_t)g * 256 + X) * 100 + 64 + lane];
    }
    red += c2s[lane] * w2a;
    if (lane < 36)
        red += c2s[64 + lane] * w2b;
    #pragma unroll
    for (int off = 32; off; off >>= 1) red += __shfl_xor(red, off);
    if (lane < 16) yp[wave][lane] = red * R[((size_t)bp * 256 + X) * 16 + lane];
    __syncthreads();
    if (tid < 16) {
        float s = yp[0][tid] + yp[1][tid] + yp[2][tid] + yp[3][tid];
        atomicAdd(&out[bp * 16 + tid], s);
    }
}

// ---------------------------------------------------------------------------
extern "C" void kernel_launch(void* const* d_in, const int* in_sizes, int n_in,
                              void* d_out, int out_size, void* d_ws, size_t ws_size,
                              hipStream_t stream)
{
    const float* x   = (const float*)d_in[0];
    const float* K   = (const float*)d_in[1];
    const float* Q   = (const float*)d_in[2];
    const float* V   = (const float*)d_in[3];
    const float* Aoo = (const float*)d_in[4];
    const float* Ann = (const float*)d_in[5];
    const float* Aon = (const float*)d_in[6];
    const float* Ano = (const float*)d_in[7];
    const float* wv  = (const float*)d_in[8];
    float* out = (float*)d_out;

    char* ws = (char*)d_ws;
    const size_t o_Qh   = 0;                                  // 2 MB
    const size_t o_Kh   = o_Qh + (size_t)2 * 1024 * 1024;     // 2 MB
    const size_t o_ut   = o_Kh + (size_t)2 * 1024 * 1024;     // 384 KB (pad .5 MB)
    const size_t o_kvtp = o_ut + (size_t)512 * 1024;          // KS*6 MB (fp16)
    const size_t o_Sp   = o_kvtp + (size_t)KS * KVT_STRIDE * 2;
    const size_t o_Sq   = o_Sp + (size_t)512 * 4400 * 4;
    const size_t o_W2   = o_Sq + (size_t)35200 * 4 + 64;      // 4*256*100 f32
    const size_t o_R    = o_W2 + (size_t)102400 * 4;          // 4*256*16 f32

    __half* Qh  = (__half*)(ws + o_Qh);
    __half* Kh  = (__half*)(ws + o_Kh);
    __half* u_t = (__half*)(ws + o_ut);
    __half* kvtp = (__half*)(ws + o_kvtp);
    float* Sp   = (float*)(ws + o_Sp);
    float* Sq   = (float*)(ws + o_Sq);
    float* W2p  = (float*)(ws + o_W2);
    float* R    = (float*)(ws + o_R);

    hipLaunchKernelGGL(prep_kernel, dim3(560),  dim3(256), 0, stream,
                       K, Q, x, Kh, Qh, u_t);
    hipLaunchKernelGGL(gemm_kvt,    dim3(768),  dim3(256), 0, stream, Kh, Qh, u_t, kvtp);
    hipLaunchKernelGGL(mid_kernel,  dim3(1280), dim3(256), 0, stream,
                       Ano, kvtp, V, x, Aon, wv, Sp, R, W2p);
    hipLaunchKernelGGL(reduce_s,    dim3(352),  dim3(128), 0, stream, Sp, Sq, out);
    hipLaunchKernelGGL(hw_kernel,   dim3(256),  dim3(256), 0, stream,
                       Aoo, wv, kvtp, W2p, Sq, Ann, R, out);
}